// Round 1
// baseline (226.183 us; speedup 1.0000x reference)
//
#include <hip/hip_runtime.h>
#include <hip/hip_bf16.h>
#include <cstddef>

#define B    4
#define DEC  256
#define ENC  1024
#define HID  512
#define UNITS 128

// fast tanh: tanh(x) = 1 - 2/(1+e^{2x})
__device__ __forceinline__ float fast_tanh(float x) {
    float z = __expf(x + x);               // v_exp_f32 path
    return 1.0f - 2.0f * __builtin_amdgcn_rcpf(1.0f + z);
}

// ---------------------------------------------------------------------------
// Kernel A: projections. Rows 0..1023 -> qbuf = query@W1 ; rows 1024..5119 ->
// kbuf = value@W2. 16 rows per block staged in LDS; thread (u, half) computes
// 8 rows x 1 unit.
// ---------------------------------------------------------------------------
__global__ __launch_bounds__(256) void proj_kernel(
    const float* __restrict__ query, const float* __restrict__ value,
    const float* __restrict__ W1,    const float* __restrict__ W2,
    float* __restrict__ qbuf,        float* __restrict__ kbuf)
{
    __shared__ float xs[16 * HID];   // 32 KB
    const int blk = blockIdx.x;
    const float* X; const float* W; float* O; int row0;
    if (blk < (B * DEC) / 16) { row0 = blk * 16;                X = query; W = W1; O = qbuf; }
    else                      { row0 = (blk - (B*DEC)/16) * 16; X = value; W = W2; O = kbuf; }

    // stage 16 contiguous rows (16*512 floats) into LDS, coalesced float4
    const float4* Xv = (const float4*)(X + (size_t)row0 * HID);
    float4* xsv = (float4*)xs;
    for (int i = threadIdx.x; i < 16 * HID / 4; i += 256) xsv[i] = Xv[i];
    __syncthreads();

    const int u    = threadIdx.x & (UNITS - 1);
    const int half = threadIdx.x >> 7;          // 0 or 1, wave-uniform
    const float* xb = xs + half * 8 * HID;

    float acc[8] = {0.f,0.f,0.f,0.f,0.f,0.f,0.f,0.f};
    for (int h = 0; h < HID; h += 4) {
        float w0 = W[(h+0) * UNITS + u];
        float w1 = W[(h+1) * UNITS + u];
        float w2 = W[(h+2) * UNITS + u];
        float w3 = W[(h+3) * UNITS + u];
        #pragma unroll
        for (int r = 0; r < 8; ++r) {
            float4 xv = *(const float4*)&xb[r * HID + h];   // LDS b128 broadcast
            acc[r] += xv.x * w0 + xv.y * w1 + xv.z * w2 + xv.w * w3;
        }
    }
    #pragma unroll
    for (int r = 0; r < 8; ++r)
        O[(size_t)(row0 + half * 8 + r) * UNITS + u] = acc[r];
}

// ---------------------------------------------------------------------------
// Kernel B: per (b, dec-row): scores (tanh) -> masked softmax -> context.
// 256 threads/block, 1024 blocks. XCD-swizzled so each b sticks to 2 XCDs.
// ---------------------------------------------------------------------------
__global__ __launch_bounds__(256) void attn_kernel(
    const float* __restrict__ qbuf, const float* __restrict__ kbuf,
    const float* __restrict__ value, const int* __restrict__ mask,
    const float* __restrict__ scale,
    float* __restrict__ ctx_out, float* __restrict__ attn_out)
{
    __shared__ float qs[UNITS];
    __shared__ float ss[UNITS];
    __shared__ float scores[ENC];
    __shared__ float red[8];

    // swizzle: xcd = x%8 ; b = xcd>>1 ; dq = (x/8)*2 + (xcd&1)
    const int x   = blockIdx.x;
    const int xcd = x & 7;
    const int b   = xcd >> 1;
    const int dq  = (x >> 3) * 2 + (xcd & 1);
    const int tid = threadIdx.x;

    if (tid < UNITS) {
        qs[tid] = qbuf[(size_t)(b * DEC + dq) * UNITS + tid];
        ss[tid] = scale[tid];
    }
    __syncthreads();

    // ---- scores ----
    float my[4];
    const float4* q4 = (const float4*)qs;
    const float4* s4 = (const float4*)ss;
    #pragma unroll
    for (int ei = 0; ei < 4; ++ei) {
        const int e = tid + ei * 256;
        float s;
        if (mask[b * ENC + e] != 0) {
            const float4* k4 = (const float4*)(kbuf + (size_t)(b * ENC + e) * UNITS);
            s = 0.f;
            #pragma unroll 8
            for (int i = 0; i < UNITS / 4; ++i) {
                float4 kv = k4[i], qv = q4[i], sv = s4[i];
                s += sv.x * fast_tanh(qv.x + kv.x);
                s += sv.y * fast_tanh(qv.y + kv.y);
                s += sv.z * fast_tanh(qv.z + kv.z);
                s += sv.w * fast_tanh(qv.w + kv.w);
            }
        } else {
            s = -1e9f;
        }
        my[ei] = s;
    }

    // ---- max reduce ----
    float lm = fmaxf(fmaxf(my[0], my[1]), fmaxf(my[2], my[3]));
    #pragma unroll
    for (int off = 32; off > 0; off >>= 1) lm = fmaxf(lm, __shfl_down(lm, off, 64));
    if ((tid & 63) == 0) red[tid >> 6] = lm;
    __syncthreads();
    const float m = fmaxf(fmaxf(red[0], red[1]), fmaxf(red[2], red[3]));

    // ---- exp & sum ----
    float lsum = 0.f;
    float w[4];
    #pragma unroll
    for (int ei = 0; ei < 4; ++ei) {
        w[ei] = __expf(my[ei] - m);
        lsum += w[ei];
    }
    #pragma unroll
    for (int off = 32; off > 0; off >>= 1) lsum += __shfl_down(lsum, off, 64);
    if ((tid & 63) == 0) red[4 + (tid >> 6)] = lsum;
    __syncthreads();
    const float inv = 1.0f / (red[4] + red[5] + red[6] + red[7]);

    // ---- normalize, store weights ----
    float* attn_row = attn_out + (size_t)(b * DEC + dq) * ENC;
    #pragma unroll
    for (int ei = 0; ei < 4; ++ei) {
        const int e = tid + ei * 256;
        const float wn = w[ei] * inv;
        scores[e] = wn;
        attn_row[e] = wn;
    }
    __syncthreads();

    // ---- context: ctx[h] = sum_e w[e] * value[b,e,h] ----
    const float* vbase = value + (size_t)b * ENC * HID;
    float* ctx_row = ctx_out + (size_t)(b * DEC + dq) * HID;
    for (int h = tid; h < HID; h += 256) {
        const float* vp = vbase + h;
        float acc0 = 0.f, acc1 = 0.f, acc2 = 0.f, acc3 = 0.f;
        for (int e = 0; e < ENC; e += 4) {
            acc0 += scores[e + 0] * vp[(size_t)(e + 0) * HID];
            acc1 += scores[e + 1] * vp[(size_t)(e + 1) * HID];
            acc2 += scores[e + 2] * vp[(size_t)(e + 2) * HID];
            acc3 += scores[e + 3] * vp[(size_t)(e + 3) * HID];
        }
        ctx_row[h] = (acc0 + acc1) + (acc2 + acc3);
    }
}

extern "C" void kernel_launch(void* const* d_in, const int* in_sizes, int n_in,
                              void* d_out, int out_size, void* d_ws, size_t ws_size,
                              hipStream_t stream) {
    const float* query = (const float*)d_in[0];
    const float* value = (const float*)d_in[1];
    const int*   mask  = (const int*)  d_in[2];
    const float* W1    = (const float*)d_in[3];
    const float* W2    = (const float*)d_in[4];
    const float* scale = (const float*)d_in[5];

    float* qbuf = (float*)d_ws;                               // B*DEC*UNITS = 131072 floats
    float* kbuf = qbuf + (size_t)B * DEC * UNITS;             // B*ENC*UNITS = 524288 floats

    float* ctx_out  = (float*)d_out;                          // B*DEC*HID
    float* attn_out = ctx_out + (size_t)B * DEC * HID;        // B*DEC*ENC

    dim3 gridA((B * DEC + B * ENC) / 16);  // 320 blocks
    proj_kernel<<<gridA, 256, 0, stream>>>(query, value, W1, W2, qbuf, kbuf);

    dim3 gridB(B * DEC);                   // 1024 blocks
    attn_kernel<<<gridB, 256, 0, stream>>>(qbuf, kbuf, value, mask, scale,
                                           ctx_out, attn_out);
}

// Round 2
// 194.727 us; speedup vs baseline: 1.1615x; 1.1615x over previous
//
#include <hip/hip_runtime.h>
#include <cstddef>

#define B     4
#define DEC   256
#define ENC   1024
#define HID   512
#define UNITS 128

// proj outputs are scaled by 2*log2(e) so the score kernel can use raw v_exp_f32
// (2^x) for tanh(x) = 1 - 2/(1+e^{2x}) = 1 - 2/(1+2^{(2*log2e)*x}).
#define PROJ_SCALE 2.8853900817779268f   // 2 * log2(e)

// ---------------------------------------------------------------------------
// Kernel 1: projections. No LDS: X-row reads are wave-uniform (scalar loads),
// W reads are lane-coalesced from L2. Each wave: 8 rows x 128 units
// (2 units/lane). q rows -> qbuf row-major; k rows -> kbufT transposed layout
// [b][c=u/4][e][u%4] so the score kernel's k loads are coalesced b128.
// ---------------------------------------------------------------------------
__global__ __launch_bounds__(256) void proj_kernel(
    const float* __restrict__ query, const float* __restrict__ value,
    const float* __restrict__ W1,    const float* __restrict__ W2,
    float* __restrict__ qbuf,        float* __restrict__ kbufT)
{
    const int lane = threadIdx.x & 63;
    const int wv   = __builtin_amdgcn_readfirstlane((int)(threadIdx.x >> 6));
    const int row0g = blockIdx.x * 32 + wv * 8;
    const bool isQ = row0g < B * DEC;
    const float* X = isQ ? query : value;
    const float* W = isQ ? W1 : W2;
    const int row0 = isQ ? row0g : row0g - B * DEC;

    float acc0[8], acc1[8];
    #pragma unroll
    for (int r = 0; r < 8; ++r) { acc0[r] = 0.f; acc1[r] = 0.f; }

    const float* Xb = X + (size_t)row0 * HID;
    for (int h = 0; h < HID; h += 4) {
        const float wa0 = W[(h+0)*UNITS + lane], wb0 = W[(h+0)*UNITS + 64 + lane];
        const float wa1 = W[(h+1)*UNITS + lane], wb1 = W[(h+1)*UNITS + 64 + lane];
        const float wa2 = W[(h+2)*UNITS + lane], wb2 = W[(h+2)*UNITS + 64 + lane];
        const float wa3 = W[(h+3)*UNITS + lane], wb3 = W[(h+3)*UNITS + 64 + lane];
        #pragma unroll
        for (int r = 0; r < 8; ++r) {
            const float4 xv = *(const float4*)(Xb + r * HID + h);  // wave-uniform
            acc0[r] += xv.x*wa0 + xv.y*wa1 + xv.z*wa2 + xv.w*wa3;
            acc1[r] += xv.x*wb0 + xv.y*wb1 + xv.z*wb2 + xv.w*wb3;
        }
    }

    if (isQ) {
        #pragma unroll
        for (int r = 0; r < 8; ++r) {
            qbuf[(size_t)(row0+r)*UNITS + lane]      = PROJ_SCALE * acc0[r];
            qbuf[(size_t)(row0+r)*UNITS + 64 + lane] = PROJ_SCALE * acc1[r];
        }
    } else {
        const int c0 = lane >> 2, j0 = lane & 3;   // u = lane -> (c0, j0); u+64 -> (c0+16, j0)
        #pragma unroll
        for (int r = 0; r < 8; ++r) {
            const int rk = row0 + r;
            const int bb = rk >> 10, e = rk & (ENC - 1);
            float* base = kbufT + ((size_t)bb * 32 * ENC + e) * 4;
            base[(size_t)c0       * ENC * 4 + j0] = PROJ_SCALE * acc0[r];
            base[(size_t)(c0+16)  * ENC * 4 + j0] = PROJ_SCALE * acc1[r];
        }
    }
}

// rcp(1 + 2^a)  (a already includes the 2*log2e factor)
__device__ __forceinline__ float sig_r(float a) {
    return __builtin_amdgcn_rcpf(1.f + __builtin_amdgcn_exp2f(a));
}

// ---------------------------------------------------------------------------
// Kernel 2: scores + masked softmax. DQ=2 dec rows per block, 512 blocks.
// score = S0 - 2 * sum_u scale_u * rcp(1 + 2^(q2+k2)).  q reads are uniform
// (scalar), k reads coalesced b128 from kbufT.
// ---------------------------------------------------------------------------
__global__ __launch_bounds__(256) void score_kernel(
    const float* __restrict__ qbuf, const float* __restrict__ kbufT,
    const int* __restrict__ mask,   const float* __restrict__ scale,
    float* __restrict__ attn_out)
{
    const int bi  = blockIdx.x;        // 0..511
    const int b   = bi >> 7;
    const int dq0 = (bi & 127) * 2;
    const int tid = threadIdx.x;

    // S0 = sum(scale) — uniform scalar loop
    float S0 = 0.f;
    for (int j = 0; j < UNITS; j += 4) {
        const float4 sv = *(const float4*)(scale + j);
        S0 += (sv.x + sv.y) + (sv.z + sv.w);
    }

    const float* q0 = qbuf + (size_t)(b * DEC + dq0) * UNITS;
    const float* q1 = q0 + UNITS;
    const float* kb = kbufT + (size_t)b * 32 * ENC * 4;

    float t0[4] = {0.f,0.f,0.f,0.f}, t1[4] = {0.f,0.f,0.f,0.f};
    for (int i = 0; i < 32; ++i) {
        const float4 qa = *(const float4*)(q0 + i * 4);       // uniform
        const float4 qb = *(const float4*)(q1 + i * 4);       // uniform
        const float4 sv = *(const float4*)(scale + i * 4);    // uniform
        const float* kc = kb + (size_t)i * ENC * 4;
        #pragma unroll
        for (int ei = 0; ei < 4; ++ei) {
            const int e = tid + ei * 256;
            const float4 kv = *(const float4*)(kc + (size_t)e * 4);  // coalesced b128
            t0[ei] += sv.x * sig_r(qa.x + kv.x);
            t0[ei] += sv.y * sig_r(qa.y + kv.y);
            t0[ei] += sv.z * sig_r(qa.z + kv.z);
            t0[ei] += sv.w * sig_r(qa.w + kv.w);
            t1[ei] += sv.x * sig_r(qb.x + kv.x);
            t1[ei] += sv.y * sig_r(qb.y + kv.y);
            t1[ei] += sv.z * sig_r(qb.z + kv.z);
            t1[ei] += sv.w * sig_r(qb.w + kv.w);
        }
    }

    float s0[4], s1[4];
    #pragma unroll
    for (int ei = 0; ei < 4; ++ei) {
        const int m = mask[b * ENC + tid + ei * 256];
        s0[ei] = m ? (S0 - 2.f * t0[ei]) : -1e9f;
        s1[ei] = m ? (S0 - 2.f * t1[ei]) : -1e9f;
    }

    __shared__ float redm[2][4];
    __shared__ float reds[2][4];
    const int lane = tid & 63, wv = tid >> 6;

    // max reduce (both dq rows together)
    float lm0 = fmaxf(fmaxf(s0[0], s0[1]), fmaxf(s0[2], s0[3]));
    float lm1 = fmaxf(fmaxf(s1[0], s1[1]), fmaxf(s1[2], s1[3]));
    #pragma unroll
    for (int off = 32; off > 0; off >>= 1) {
        lm0 = fmaxf(lm0, __shfl_down(lm0, off, 64));
        lm1 = fmaxf(lm1, __shfl_down(lm1, off, 64));
    }
    if (lane == 0) { redm[0][wv] = lm0; redm[1][wv] = lm1; }
    __syncthreads();
    const float gm0 = fmaxf(fmaxf(redm[0][0], redm[0][1]), fmaxf(redm[0][2], redm[0][3]));
    const float gm1 = fmaxf(fmaxf(redm[1][0], redm[1][1]), fmaxf(redm[1][2], redm[1][3]));

    // exp & sum
    float w0[4], w1[4];
    float ls0 = 0.f, ls1 = 0.f;
    #pragma unroll
    for (int ei = 0; ei < 4; ++ei) {
        w0[ei] = __expf(s0[ei] - gm0); ls0 += w0[ei];
        w1[ei] = __expf(s1[ei] - gm1); ls1 += w1[ei];
    }
    #pragma unroll
    for (int off = 32; off > 0; off >>= 1) {
        ls0 += __shfl_down(ls0, off, 64);
        ls1 += __shfl_down(ls1, off, 64);
    }
    if (lane == 0) { reds[0][wv] = ls0; reds[1][wv] = ls1; }
    __syncthreads();
    const float inv0 = __builtin_amdgcn_rcpf(reds[0][0] + reds[0][1] + reds[0][2] + reds[0][3]);
    const float inv1 = __builtin_amdgcn_rcpf(reds[1][0] + reds[1][1] + reds[1][2] + reds[1][3]);

    float* a0 = attn_out + (size_t)(b * DEC + dq0) * ENC;
    float* a1 = a0 + ENC;
    #pragma unroll
    for (int ei = 0; ei < 4; ++ei) {
        const int e = tid + ei * 256;
        a0[e] = w0[ei] * inv0;
        a1[e] = w1[ei] * inv1;
    }
}

// ---------------------------------------------------------------------------
// Kernel 3: ctx = attn @ value. 512 blocks: 8 dec rows x 128 h-cols each.
// Weights broadcast lane->wave via v_readlane (no per-e LDS reads).
// Each wave handles a 256-e quarter; 4-way cross-wave reduce via LDS.
// ---------------------------------------------------------------------------
__global__ __launch_bounds__(256) void ctx_kernel(
    const float* __restrict__ attn, const float* __restrict__ value,
    float* __restrict__ ctx)
{
    __shared__ float attnS[8][ENC];     // 32 KB
    __shared__ float part[4][8][128];   // 16 KB

    const int bi   = blockIdx.x;                 // 0..511, XCD-swizzled
    const int b    = (bi >> 1) & 3;              // b pinned to an XCD pair
    const int idx  = ((bi >> 3) << 1) | (bi & 1);
    const int row0 = (idx >> 2) * 8;
    const int h0   = (idx & 3) * 128;
    const int tid  = threadIdx.x;
    const int lane = tid & 63;
    const int wv   = __builtin_amdgcn_readfirstlane(tid >> 6);

    // stage 8 attention rows (coalesced b128)
    #pragma unroll
    for (int r = 0; r < 8; ++r) {
        const float4 v = *(const float4*)(attn + (size_t)(b * DEC + row0 + r) * ENC + tid * 4);
        *(float4*)&attnS[r][tid * 4] = v;
    }
    __syncthreads();

    float acc[8][2];
    #pragma unroll
    for (int r = 0; r < 8; ++r) { acc[r][0] = 0.f; acc[r][1] = 0.f; }

    const float* vb = value + (size_t)b * ENC * HID + h0 + lane * 2;
    const int eq = wv * 256;
    for (int ec = 0; ec < 4; ++ec) {
        const int e0 = eq + ec * 64;
        float sc[8];
        #pragma unroll
        for (int r = 0; r < 8; ++r) sc[r] = attnS[r][e0 + lane];  // stride-1, conflict-free
        const float* vp = vb + (size_t)e0 * HID;
        #pragma unroll
        for (int l = 0; l < 64; ++l) {
            const float2 v2 = *(const float2*)(vp + (size_t)l * HID);  // coalesced b64
            #pragma unroll
            for (int r = 0; r < 8; ++r) {
                const float w = __builtin_bit_cast(float,
                    __builtin_amdgcn_readlane(__builtin_bit_cast(int, sc[r]), l));
                acc[r][0] += w * v2.x;
                acc[r][1] += w * v2.y;
            }
        }
    }

    #pragma unroll
    for (int r = 0; r < 8; ++r)
        *(float2*)&part[wv][r][lane * 2] = make_float2(acc[r][0], acc[r][1]);
    __syncthreads();

    // 4-way cross-wave reduce; each thread produces one float4 of output
    const int r  = tid >> 5;          // 0..7
    const int hh = (tid & 31) * 4;    // 0..124
    float4 s = make_float4(0.f, 0.f, 0.f, 0.f);
    #pragma unroll
    for (int w = 0; w < 4; ++w) {
        const float4 p = *(const float4*)&part[w][r][hh];
        s.x += p.x; s.y += p.y; s.z += p.z; s.w += p.w;
    }
    *(float4*)(ctx + (size_t)(b * DEC + row0 + r) * HID + h0 + hh) = s;
}

extern "C" void kernel_launch(void* const* d_in, const int* in_sizes, int n_in,
                              void* d_out, int out_size, void* d_ws, size_t ws_size,
                              hipStream_t stream) {
    const float* query = (const float*)d_in[0];
    const float* value = (const float*)d_in[1];
    const int*   mask  = (const int*)  d_in[2];
    const float* W1    = (const float*)d_in[3];
    const float* W2    = (const float*)d_in[4];
    const float* scale = (const float*)d_in[5];

    float* qbuf  = (float*)d_ws;                       // B*DEC*UNITS   = 131072 floats
    float* kbufT = qbuf + (size_t)B * DEC * UNITS;     // B*32*ENC*4    = 524288 floats

    float* ctx_out  = (float*)d_out;                   // B*DEC*HID
    float* attn_out = ctx_out + (size_t)B * DEC * HID; // B*DEC*ENC

    proj_kernel <<<160, 256, 0, stream>>>(query, value, W1, W2, qbuf, kbufT);
    score_kernel<<<512, 256, 0, stream>>>(qbuf, kbufT, mask, scale, attn_out);
    ctx_kernel  <<<512, 256, 0, stream>>>(attn_out, value, ctx_out);
}

// Round 3
// 161.155 us; speedup vs baseline: 1.4035x; 1.2083x over previous
//
#include <hip/hip_runtime.h>
#include <cstddef>

#define B     4
#define DEC   256
#define ENC   1024
#define HID   512
#define UNITS 128

// proj outputs are scaled by 2*log2(e) so the score kernel can use raw v_exp_f32
// (2^x) for tanh(x) = 1 - 2/(1+e^{2x}) = 1 - 2/(1+2^{(2*log2e)*x}).
#define PROJ_SCALE 2.8853900817779268f   // 2 * log2(e)

// ---------------------------------------------------------------------------
// Kernel 1: projections. Block = 8 rows x 128 units; each wave handles a
// 128-wide h-quarter (all 8 rows), partials reduced across waves via LDS.
// X reads are wave-uniform (scalar pipe); W reads lane-coalesced b32 from L2.
// 640 blocks -> 2560 waves (2.5/SIMD) for latency hiding (round-2 had 0.6).
// q rows -> qbuf row-major; k rows -> kbufT [b][c=u/4][e][u%4] so the score
// kernel's k loads are coalesced b128.
// ---------------------------------------------------------------------------
__global__ __launch_bounds__(256) void proj_kernel(
    const float* __restrict__ query, const float* __restrict__ value,
    const float* __restrict__ W1,    const float* __restrict__ W2,
    float* __restrict__ qbuf,        float* __restrict__ kbufT)
{
    __shared__ float part[4][8][UNITS];   // 16 KB

    const int tid  = threadIdx.x;
    const int lane = tid & 63;
    const int wv   = __builtin_amdgcn_readfirstlane(tid >> 6);
    const int row0g = blockIdx.x * 8;
    const bool isQ = row0g < B * DEC;
    const float* X = isQ ? query : value;
    const float* W = isQ ? W1 : W2;
    const int row0 = isQ ? row0g : row0g - B * DEC;
    const int h0   = wv * 128;            // this wave's h-quarter

    float acc0[8], acc1[8];
    #pragma unroll
    for (int r = 0; r < 8; ++r) { acc0[r] = 0.f; acc1[r] = 0.f; }

    const float* Xb = X + (size_t)row0 * HID + h0;
    const float* Wb = W + (size_t)h0 * UNITS;

    for (int h = 0; h < 128; h += 4) {
        const float wa0 = Wb[(h+0)*UNITS + lane], wb0 = Wb[(h+0)*UNITS + 64 + lane];
        const float wa1 = Wb[(h+1)*UNITS + lane], wb1 = Wb[(h+1)*UNITS + 64 + lane];
        const float wa2 = Wb[(h+2)*UNITS + lane], wb2 = Wb[(h+2)*UNITS + 64 + lane];
        const float wa3 = Wb[(h+3)*UNITS + lane], wb3 = Wb[(h+3)*UNITS + 64 + lane];
        #pragma unroll
        for (int r = 0; r < 8; ++r) {
            const float4 xv = *(const float4*)(Xb + r * HID + h);  // wave-uniform -> s_load
            acc0[r] += xv.x*wa0 + xv.y*wa1 + xv.z*wa2 + xv.w*wa3;
            acc1[r] += xv.x*wb0 + xv.y*wb1 + xv.z*wb2 + xv.w*wb3;
        }
    }

    #pragma unroll
    for (int r = 0; r < 8; ++r) {
        part[wv][r][lane]      = acc0[r];
        part[wv][r][64 + lane] = acc1[r];
    }
    __syncthreads();

    // cross-wave reduce: 1024 outputs, 4 per thread, stride-1 in u (no conflicts)
    #pragma unroll
    for (int k = 0; k < 4; ++k) {
        const int idx = tid + k * 256;
        const int r = idx >> 7, u = idx & (UNITS - 1);
        const float s = PROJ_SCALE *
            ((part[0][r][u] + part[1][r][u]) + (part[2][r][u] + part[3][r][u]));
        const int row = row0 + r;
        if (isQ) {
            qbuf[(size_t)row * UNITS + u] = s;
        } else {
            const int bb = row >> 10, e = row & (ENC - 1);
            const int c = u >> 2, j = u & 3;
            kbufT[((size_t)bb * 32 * ENC + (size_t)c * ENC + e) * 4 + j] = s;
        }
    }
}

// rcp(1 + 2^a)  (a already includes the 2*log2e factor)
__device__ __forceinline__ float sig_r(float a) {
    return __builtin_amdgcn_rcpf(1.f + __builtin_amdgcn_exp2f(a));
}

// ---------------------------------------------------------------------------
// Kernel 2: scores + masked softmax. DQ=2 dec rows per block, 512 blocks.
// score = S0 - 2 * sum_u scale_u * rcp(1 + 2^(q2+k2)).  q reads are uniform
// (scalar), k reads coalesced b128 from kbufT.
// ---------------------------------------------------------------------------
__global__ __launch_bounds__(256) void score_kernel(
    const float* __restrict__ qbuf, const float* __restrict__ kbufT,
    const int* __restrict__ mask,   const float* __restrict__ scale,
    float* __restrict__ attn_out)
{
    const int bi  = blockIdx.x;        // 0..511
    const int b   = bi >> 7;
    const int dq0 = (bi & 127) * 2;
    const int tid = threadIdx.x;

    // S0 = sum(scale) — uniform scalar loop
    float S0 = 0.f;
    for (int j = 0; j < UNITS; j += 4) {
        const float4 sv = *(const float4*)(scale + j);
        S0 += (sv.x + sv.y) + (sv.z + sv.w);
    }

    const float* q0 = qbuf + (size_t)(b * DEC + dq0) * UNITS;
    const float* q1 = q0 + UNITS;
    const float* kb = kbufT + (size_t)b * 32 * ENC * 4;

    float t0[4] = {0.f,0.f,0.f,0.f}, t1[4] = {0.f,0.f,0.f,0.f};
    for (int i = 0; i < 32; ++i) {
        const float4 qa = *(const float4*)(q0 + i * 4);       // uniform
        const float4 qb = *(const float4*)(q1 + i * 4);       // uniform
        const float4 sv = *(const float4*)(scale + i * 4);    // uniform
        const float* kc = kb + (size_t)i * ENC * 4;
        #pragma unroll
        for (int ei = 0; ei < 4; ++ei) {
            const int e = tid + ei * 256;
            const float4 kv = *(const float4*)(kc + (size_t)e * 4);  // coalesced b128
            t0[ei] += sv.x * sig_r(qa.x + kv.x);
            t0[ei] += sv.y * sig_r(qa.y + kv.y);
            t0[ei] += sv.z * sig_r(qa.z + kv.z);
            t0[ei] += sv.w * sig_r(qa.w + kv.w);
            t1[ei] += sv.x * sig_r(qb.x + kv.x);
            t1[ei] += sv.y * sig_r(qb.y + kv.y);
            t1[ei] += sv.z * sig_r(qb.z + kv.z);
            t1[ei] += sv.w * sig_r(qb.w + kv.w);
        }
    }

    float s0[4], s1[4];
    #pragma unroll
    for (int ei = 0; ei < 4; ++ei) {
        const int m = mask[b * ENC + tid + ei * 256];
        s0[ei] = m ? (S0 - 2.f * t0[ei]) : -1e9f;
        s1[ei] = m ? (S0 - 2.f * t1[ei]) : -1e9f;
    }

    __shared__ float redm[2][4];
    __shared__ float reds[2][4];
    const int lane = tid & 63, wv = tid >> 6;

    // max reduce (both dq rows together)
    float lm0 = fmaxf(fmaxf(s0[0], s0[1]), fmaxf(s0[2], s0[3]));
    float lm1 = fmaxf(fmaxf(s1[0], s1[1]), fmaxf(s1[2], s1[3]));
    #pragma unroll
    for (int off = 32; off > 0; off >>= 1) {
        lm0 = fmaxf(lm0, __shfl_down(lm0, off, 64));
        lm1 = fmaxf(lm1, __shfl_down(lm1, off, 64));
    }
    if (lane == 0) { redm[0][wv] = lm0; redm[1][wv] = lm1; }
    __syncthreads();
    const float gm0 = fmaxf(fmaxf(redm[0][0], redm[0][1]), fmaxf(redm[0][2], redm[0][3]));
    const float gm1 = fmaxf(fmaxf(redm[1][0], redm[1][1]), fmaxf(redm[1][2], redm[1][3]));

    // exp & sum
    float w0[4], w1[4];
    float ls0 = 0.f, ls1 = 0.f;
    #pragma unroll
    for (int ei = 0; ei < 4; ++ei) {
        w0[ei] = __expf(s0[ei] - gm0); ls0 += w0[ei];
        w1[ei] = __expf(s1[ei] - gm1); ls1 += w1[ei];
    }
    #pragma unroll
    for (int off = 32; off > 0; off >>= 1) {
        ls0 += __shfl_down(ls0, off, 64);
        ls1 += __shfl_down(ls1, off, 64);
    }
    if (lane == 0) { reds[0][wv] = ls0; reds[1][wv] = ls1; }
    __syncthreads();
    const float inv0 = __builtin_amdgcn_rcpf(reds[0][0] + reds[0][1] + reds[0][2] + reds[0][3]);
    const float inv1 = __builtin_amdgcn_rcpf(reds[1][0] + reds[1][1] + reds[1][2] + reds[1][3]);

    float* a0 = attn_out + (size_t)(b * DEC + dq0) * ENC;
    float* a1 = a0 + ENC;
    #pragma unroll
    for (int ei = 0; ei < 4; ++ei) {
        const int e = tid + ei * 256;
        a0[e] = w0[ei] * inv0;
        a1[e] = w1[ei] * inv1;
    }
}

// ---------------------------------------------------------------------------
// Kernel 3: ctx = attn @ value. 512 blocks: 8 dec rows x 128 h-cols each.
// Weights broadcast lane->wave via v_readlane (no per-e LDS reads).
// Each wave handles a 256-e quarter; 4-way cross-wave reduce via LDS.
// ---------------------------------------------------------------------------
__global__ __launch_bounds__(256) void ctx_kernel(
    const float* __restrict__ attn, const float* __restrict__ value,
    float* __restrict__ ctx)
{
    __shared__ float attnS[8][ENC];     // 32 KB
    __shared__ float part[4][8][128];   // 16 KB

    const int bi   = blockIdx.x;                 // 0..511, XCD-swizzled
    const int b    = (bi >> 1) & 3;              // b pinned to an XCD pair
    const int idx  = ((bi >> 3) << 1) | (bi & 1);
    const int row0 = (idx >> 2) * 8;
    const int h0   = (idx & 3) * 128;
    const int tid  = threadIdx.x;
    const int lane = tid & 63;
    const int wv   = __builtin_amdgcn_readfirstlane(tid >> 6);

    // stage 8 attention rows (coalesced b128)
    #pragma unroll
    for (int r = 0; r < 8; ++r) {
        const float4 v = *(const float4*)(attn + (size_t)(b * DEC + row0 + r) * ENC + tid * 4);
        *(float4*)&attnS[r][tid * 4] = v;
    }
    __syncthreads();

    float acc[8][2];
    #pragma unroll
    for (int r = 0; r < 8; ++r) { acc[r][0] = 0.f; acc[r][1] = 0.f; }

    const float* vb = value + (size_t)b * ENC * HID + h0 + lane * 2;
    const int eq = wv * 256;
    for (int ec = 0; ec < 4; ++ec) {
        const int e0 = eq + ec * 64;
        float sc[8];
        #pragma unroll
        for (int r = 0; r < 8; ++r) sc[r] = attnS[r][e0 + lane];  // stride-1, conflict-free
        const float* vp = vb + (size_t)e0 * HID;
        #pragma unroll
        for (int l = 0; l < 64; ++l) {
            const float2 v2 = *(const float2*)(vp + (size_t)l * HID);  // coalesced b64
            #pragma unroll
            for (int r = 0; r < 8; ++r) {
                const float w = __builtin_bit_cast(float,
                    __builtin_amdgcn_readlane(__builtin_bit_cast(int, sc[r]), l));
                acc[r][0] += w * v2.x;
                acc[r][1] += w * v2.y;
            }
        }
    }

    #pragma unroll
    for (int r = 0; r < 8; ++r)
        *(float2*)&part[wv][r][lane * 2] = make_float2(acc[r][0], acc[r][1]);
    __syncthreads();

    // 4-way cross-wave reduce; each thread produces one float4 of output
    const int r  = tid >> 5;          // 0..7
    const int hh = (tid & 31) * 4;    // 0..124
    float4 s = make_float4(0.f, 0.f, 0.f, 0.f);
    #pragma unroll
    for (int w = 0; w < 4; ++w) {
        const float4 p = *(const float4*)&part[w][r][hh];
        s.x += p.x; s.y += p.y; s.z += p.z; s.w += p.w;
    }
    *(float4*)(ctx + (size_t)(b * DEC + row0 + r) * HID + h0 + hh) = s;
}

extern "C" void kernel_launch(void* const* d_in, const int* in_sizes, int n_in,
                              void* d_out, int out_size, void* d_ws, size_t ws_size,
                              hipStream_t stream) {
    const float* query = (const float*)d_in[0];
    const float* value = (const float*)d_in[1];
    const int*   mask  = (const int*)  d_in[2];
    const float* W1    = (const float*)d_in[3];
    const float* W2    = (const float*)d_in[4];
    const float* scale = (const float*)d_in[5];

    float* qbuf  = (float*)d_ws;                       // B*DEC*UNITS   = 131072 floats
    float* kbufT = qbuf + (size_t)B * DEC * UNITS;     // B*32*ENC*4    = 524288 floats

    float* ctx_out  = (float*)d_out;                   // B*DEC*HID
    float* attn_out = ctx_out + (size_t)B * DEC * HID; // B*DEC*ENC

    proj_kernel <<<640, 256, 0, stream>>>(query, value, W1, W2, qbuf, kbufT);
    score_kernel<<<512, 256, 0, stream>>>(qbuf, kbufT, mask, scale, attn_out);
    ctx_kernel  <<<512, 256, 0, stream>>>(attn_out, value, ctx_out);
}

// Round 4
// 150.027 us; speedup vs baseline: 1.5076x; 1.0742x over previous
//
#include <hip/hip_runtime.h>
#include <cstddef>

#define B     4
#define DEC   256
#define ENC   1024
#define HID   512
#define UNITS 128

// proj outputs are scaled by 2*log2(e) so the score kernel can use raw v_exp_f32
// (2^x) for tanh(x) = 1 - 2/(1+e^{2x}) = 1 - 2/(1+2^{(2*log2e)*x}).
#define PROJ_SCALE 2.8853900817779268f   // 2 * log2(e)

// ---------------------------------------------------------------------------
// Kernel 1: projections. Block = 8 rows x 128 units; each wave handles a
// 128-wide h-quarter (all 8 rows), partials reduced across waves via LDS.
// X reads are wave-uniform (scalar pipe); W reads lane-coalesced b32 from L2.
// q rows -> qbuf row-major; k rows -> kbufT [b][c=u/4][e][u%4] so the score
// kernel's k loads are coalesced b128.
// ---------------------------------------------------------------------------
__global__ __launch_bounds__(256) void proj_kernel(
    const float* __restrict__ query, const float* __restrict__ value,
    const float* __restrict__ W1,    const float* __restrict__ W2,
    float* __restrict__ qbuf,        float* __restrict__ kbufT)
{
    __shared__ float part[4][8][UNITS];   // 16 KB

    const int tid  = threadIdx.x;
    const int lane = tid & 63;
    const int wv   = __builtin_amdgcn_readfirstlane(tid >> 6);
    const int row0g = blockIdx.x * 8;
    const bool isQ = row0g < B * DEC;
    const float* X = isQ ? query : value;
    const float* W = isQ ? W1 : W2;
    const int row0 = isQ ? row0g : row0g - B * DEC;
    const int h0   = wv * 128;            // this wave's h-quarter

    float acc0[8], acc1[8];
    #pragma unroll
    for (int r = 0; r < 8; ++r) { acc0[r] = 0.f; acc1[r] = 0.f; }

    const float* Xb = X + (size_t)row0 * HID + h0;
    const float* Wb = W + (size_t)h0 * UNITS;

    for (int h = 0; h < 128; h += 4) {
        const float wa0 = Wb[(h+0)*UNITS + lane], wb0 = Wb[(h+0)*UNITS + 64 + lane];
        const float wa1 = Wb[(h+1)*UNITS + lane], wb1 = Wb[(h+1)*UNITS + 64 + lane];
        const float wa2 = Wb[(h+2)*UNITS + lane], wb2 = Wb[(h+2)*UNITS + 64 + lane];
        const float wa3 = Wb[(h+3)*UNITS + lane], wb3 = Wb[(h+3)*UNITS + 64 + lane];
        #pragma unroll
        for (int r = 0; r < 8; ++r) {
            const float4 xv = *(const float4*)(Xb + r * HID + h);  // wave-uniform -> s_load
            acc0[r] += xv.x*wa0 + xv.y*wa1 + xv.z*wa2 + xv.w*wa3;
            acc1[r] += xv.x*wb0 + xv.y*wb1 + xv.z*wb2 + xv.w*wb3;
        }
    }

    #pragma unroll
    for (int r = 0; r < 8; ++r) {
        part[wv][r][lane]      = acc0[r];
        part[wv][r][64 + lane] = acc1[r];
    }
    __syncthreads();

    // cross-wave reduce: 1024 outputs, 4 per thread, stride-1 in u (no conflicts)
    #pragma unroll
    for (int k = 0; k < 4; ++k) {
        const int idx = tid + k * 256;
        const int r = idx >> 7, u = idx & (UNITS - 1);
        const float s = PROJ_SCALE *
            ((part[0][r][u] + part[1][r][u]) + (part[2][r][u] + part[3][r][u]));
        const int row = row0 + r;
        if (isQ) {
            qbuf[(size_t)row * UNITS + u] = s;
        } else {
            const int bb = row >> 10, e = row & (ENC - 1);
            const int c = u >> 2, j = u & 3;
            kbufT[((size_t)bb * 32 * ENC + (size_t)c * ENC + e) * 4 + j] = s;
        }
    }
}

// rcp(1 + 2^a)  (a already includes the 2*log2e factor)
__device__ __forceinline__ float sig_r(float a) {
    return __builtin_amdgcn_rcpf(1.f + __builtin_amdgcn_exp2f(a));
}

// ---------------------------------------------------------------------------
// Kernel 2: scores + masked softmax. DQ=2 dec rows per block, 512 blocks x
// 512 threads (8 waves -> 16 waves/CU; round-3 had 8/CU at 16% occupancy).
// score = S0 - 2 * sum_u scale_u * rcp(1 + 2^(q2+k2)).  q reads are uniform
// (scalar), k reads coalesced b128 from kbufT. XCD-swizzled: b pinned to an
// XCD pair so kbufT[b] (512 KB) stays in that pair's L2.
// ---------------------------------------------------------------------------
__global__ __launch_bounds__(512) void score_kernel(
    const float* __restrict__ qbuf, const float* __restrict__ kbufT,
    const int* __restrict__ mask,   const float* __restrict__ scale,
    float* __restrict__ attn_out)
{
    const int bi  = blockIdx.x;                      // 0..511
    const int b   = (bi >> 1) & 3;                   // XCD-pair pinning
    const int dq0 = (((bi >> 3) << 1) | (bi & 1)) * 2;
    const int tid = threadIdx.x;                     // 0..511

    // S0 = sum(scale) — uniform scalar loop
    float S0 = 0.f;
    for (int j = 0; j < UNITS; j += 4) {
        const float4 sv = *(const float4*)(scale + j);
        S0 += (sv.x + sv.y) + (sv.z + sv.w);
    }

    const float* q0 = qbuf + (size_t)(b * DEC + dq0) * UNITS;
    const float* q1 = q0 + UNITS;
    const float* kb = kbufT + (size_t)b * 32 * ENC * 4;

    float t0[2] = {0.f,0.f}, t1[2] = {0.f,0.f};
    for (int i = 0; i < 32; ++i) {
        const float4 qa = *(const float4*)(q0 + i * 4);       // uniform
        const float4 qb = *(const float4*)(q1 + i * 4);       // uniform
        const float4 sv = *(const float4*)(scale + i * 4);    // uniform
        const float* kc = kb + (size_t)i * ENC * 4;
        #pragma unroll
        for (int ei = 0; ei < 2; ++ei) {
            const int e = tid + ei * 512;
            const float4 kv = *(const float4*)(kc + (size_t)e * 4);  // coalesced b128
            t0[ei] += sv.x * sig_r(qa.x + kv.x);
            t0[ei] += sv.y * sig_r(qa.y + kv.y);
            t0[ei] += sv.z * sig_r(qa.z + kv.z);
            t0[ei] += sv.w * sig_r(qa.w + kv.w);
            t1[ei] += sv.x * sig_r(qb.x + kv.x);
            t1[ei] += sv.y * sig_r(qb.y + kv.y);
            t1[ei] += sv.z * sig_r(qb.z + kv.z);
            t1[ei] += sv.w * sig_r(qb.w + kv.w);
        }
    }

    float s0[2], s1[2];
    #pragma unroll
    for (int ei = 0; ei < 2; ++ei) {
        const int m = mask[b * ENC + tid + ei * 512];
        s0[ei] = m ? (S0 - 2.f * t0[ei]) : -1e9f;
        s1[ei] = m ? (S0 - 2.f * t1[ei]) : -1e9f;
    }

    __shared__ float redm[2][8];
    __shared__ float reds[2][8];
    const int lane = tid & 63, wv = tid >> 6;   // 8 waves

    // max reduce (both dq rows together)
    float lm0 = fmaxf(s0[0], s0[1]);
    float lm1 = fmaxf(s1[0], s1[1]);
    #pragma unroll
    for (int off = 32; off > 0; off >>= 1) {
        lm0 = fmaxf(lm0, __shfl_down(lm0, off, 64));
        lm1 = fmaxf(lm1, __shfl_down(lm1, off, 64));
    }
    if (lane == 0) { redm[0][wv] = lm0; redm[1][wv] = lm1; }
    __syncthreads();
    float gm0 = redm[0][0], gm1 = redm[1][0];
    #pragma unroll
    for (int w = 1; w < 8; ++w) {
        gm0 = fmaxf(gm0, redm[0][w]);
        gm1 = fmaxf(gm1, redm[1][w]);
    }

    // exp & sum
    float w0[2], w1[2];
    float ls0 = 0.f, ls1 = 0.f;
    #pragma unroll
    for (int ei = 0; ei < 2; ++ei) {
        w0[ei] = __expf(s0[ei] - gm0); ls0 += w0[ei];
        w1[ei] = __expf(s1[ei] - gm1); ls1 += w1[ei];
    }
    #pragma unroll
    for (int off = 32; off > 0; off >>= 1) {
        ls0 += __shfl_down(ls0, off, 64);
        ls1 += __shfl_down(ls1, off, 64);
    }
    if (lane == 0) { reds[0][wv] = ls0; reds[1][wv] = ls1; }
    __syncthreads();
    float gs0 = 0.f, gs1 = 0.f;
    #pragma unroll
    for (int w = 0; w < 8; ++w) { gs0 += reds[0][w]; gs1 += reds[1][w]; }
    const float inv0 = __builtin_amdgcn_rcpf(gs0);
    const float inv1 = __builtin_amdgcn_rcpf(gs1);

    float* a0 = attn_out + (size_t)(b * DEC + dq0) * ENC;
    float* a1 = a0 + ENC;
    #pragma unroll
    for (int ei = 0; ei < 2; ++ei) {
        const int e = tid + ei * 512;
        a0[e] = w0[ei] * inv0;
        a1[e] = w1[ei] * inv1;
    }
}

// ---------------------------------------------------------------------------
// Kernel 3: ctx = attn @ value. 512 blocks x 512 threads: 8 dec rows x 128
// h-cols per block; each of 8 waves owns a 128-e slice, loading its attention
// weights straight from global into registers (no LDS staging). Weights
// broadcast lane->wave via v_readlane; 8-way cross-wave reduce via LDS.
// ---------------------------------------------------------------------------
__global__ __launch_bounds__(512) void ctx_kernel(
    const float* __restrict__ attn, const float* __restrict__ value,
    float* __restrict__ ctx)
{
    __shared__ float part[8][8][128];   // 32 KB

    const int bi   = blockIdx.x;                 // 0..511, XCD-swizzled
    const int b    = (bi >> 1) & 3;              // b pinned to an XCD pair
    const int idx  = ((bi >> 3) << 1) | (bi & 1);
    const int row0 = (idx >> 2) * 8;
    const int h0   = (idx & 3) * 128;
    const int tid  = threadIdx.x;
    const int lane = tid & 63;
    const int wv   = __builtin_amdgcn_readfirstlane(tid >> 6);  // 0..7

    float acc[8][2];
    #pragma unroll
    for (int r = 0; r < 8; ++r) { acc[r][0] = 0.f; acc[r][1] = 0.f; }

    const float* vb = value + (size_t)b * ENC * HID + h0 + lane * 2;
    const float* ab = attn + (size_t)(b * DEC + row0) * ENC;

    #pragma unroll
    for (int ec = 0; ec < 2; ++ec) {
        const int e0 = wv * 128 + ec * 64;
        float sc[8];
        #pragma unroll
        for (int r = 0; r < 8; ++r)
            sc[r] = ab[(size_t)r * ENC + e0 + lane];   // coalesced global b32
        const float* vp = vb + (size_t)e0 * HID;
        #pragma unroll
        for (int l = 0; l < 64; ++l) {
            const float2 v2 = *(const float2*)(vp + (size_t)l * HID);  // coalesced b64
            #pragma unroll
            for (int r = 0; r < 8; ++r) {
                const float w = __builtin_bit_cast(float,
                    __builtin_amdgcn_readlane(__builtin_bit_cast(int, sc[r]), l));
                acc[r][0] += w * v2.x;
                acc[r][1] += w * v2.y;
            }
        }
    }

    #pragma unroll
    for (int r = 0; r < 8; ++r)
        *(float2*)&part[wv][r][lane * 2] = make_float2(acc[r][0], acc[r][1]);
    __syncthreads();

    // 8-way cross-wave reduce: 1024 outputs, 2 per thread, stride-1 in h
    #pragma unroll
    for (int k = 0; k < 2; ++k) {
        const int idx2 = tid + k * 512;
        const int r = idx2 >> 7, hh = idx2 & 127;
        float s = 0.f;
        #pragma unroll
        for (int w = 0; w < 8; ++w) s += part[w][r][hh];
        ctx[(size_t)(b * DEC + row0 + r) * HID + h0 + hh] = s;
    }
}

extern "C" void kernel_launch(void* const* d_in, const int* in_sizes, int n_in,
                              void* d_out, int out_size, void* d_ws, size_t ws_size,
                              hipStream_t stream) {
    const float* query = (const float*)d_in[0];
    const float* value = (const float*)d_in[1];
    const int*   mask  = (const int*)  d_in[2];
    const float* W1    = (const float*)d_in[3];
    const float* W2    = (const float*)d_in[4];
    const float* scale = (const float*)d_in[5];

    float* qbuf  = (float*)d_ws;                       // B*DEC*UNITS   = 131072 floats
    float* kbufT = qbuf + (size_t)B * DEC * UNITS;     // B*32*ENC*4    = 524288 floats

    float* ctx_out  = (float*)d_out;                   // B*DEC*HID
    float* attn_out = ctx_out + (size_t)B * DEC * HID; // B*DEC*ENC

    proj_kernel <<<640, 256, 0, stream>>>(query, value, W1, W2, qbuf, kbufT);
    score_kernel<<<512, 512, 0, stream>>>(qbuf, kbufT, mask, scale, attn_out);
    ctx_kernel  <<<512, 512, 0, stream>>>(attn_out, value, ctx_out);
}

// Round 5
// 149.533 us; speedup vs baseline: 1.5126x; 1.0033x over previous
//
#include <hip/hip_runtime.h>
#include <cstddef>

#define B     4
#define DEC   256
#define ENC   1024
#define HID   512
#define UNITS 128

// proj outputs are scaled by 2*log2(e) so the score kernel can use raw v_exp_f32
// (2^x) for tanh(x) = 1 - 2/(1+e^{2x}) = 1 - 2/(1+2^{(2*log2e)*x}).
#define PROJ_SCALE 2.8853900817779268f   // 2 * log2(e)

// ---------------------------------------------------------------------------
// Kernel 1: projections. Block = 8 rows x 128 units; each wave handles a
// 128-wide h-quarter (all 8 rows), partials reduced across waves via LDS.
// X reads are wave-uniform (scalar pipe); W reads lane-coalesced b32 from L2.
// q rows -> qbuf row-major; k rows -> kbufT [b][c=u/4][e][u%4] so the score
// kernel's k loads are coalesced b128.
// ---------------------------------------------------------------------------
__global__ __launch_bounds__(256) void proj_kernel(
    const float* __restrict__ query, const float* __restrict__ value,
    const float* __restrict__ W1,    const float* __restrict__ W2,
    float* __restrict__ qbuf,        float* __restrict__ kbufT)
{
    __shared__ float part[4][8][UNITS];   // 16 KB

    const int tid  = threadIdx.x;
    const int lane = tid & 63;
    const int wv   = __builtin_amdgcn_readfirstlane(tid >> 6);
    const int row0g = blockIdx.x * 8;
    const bool isQ = row0g < B * DEC;
    const float* X = isQ ? query : value;
    const float* W = isQ ? W1 : W2;
    const int row0 = isQ ? row0g : row0g - B * DEC;
    const int h0   = wv * 128;            // this wave's h-quarter

    float acc0[8], acc1[8];
    #pragma unroll
    for (int r = 0; r < 8; ++r) { acc0[r] = 0.f; acc1[r] = 0.f; }

    const float* Xb = X + (size_t)row0 * HID + h0;
    const float* Wb = W + (size_t)h0 * UNITS;

    for (int h = 0; h < 128; h += 4) {
        const float wa0 = Wb[(h+0)*UNITS + lane], wb0 = Wb[(h+0)*UNITS + 64 + lane];
        const float wa1 = Wb[(h+1)*UNITS + lane], wb1 = Wb[(h+1)*UNITS + 64 + lane];
        const float wa2 = Wb[(h+2)*UNITS + lane], wb2 = Wb[(h+2)*UNITS + 64 + lane];
        const float wa3 = Wb[(h+3)*UNITS + lane], wb3 = Wb[(h+3)*UNITS + 64 + lane];
        #pragma unroll
        for (int r = 0; r < 8; ++r) {
            const float4 xv = *(const float4*)(Xb + r * HID + h);  // wave-uniform -> s_load
            acc0[r] += xv.x*wa0 + xv.y*wa1 + xv.z*wa2 + xv.w*wa3;
            acc1[r] += xv.x*wb0 + xv.y*wb1 + xv.z*wb2 + xv.w*wb3;
        }
    }

    #pragma unroll
    for (int r = 0; r < 8; ++r) {
        part[wv][r][lane]      = acc0[r];
        part[wv][r][64 + lane] = acc1[r];
    }
    __syncthreads();

    // cross-wave reduce: 1024 outputs, 4 per thread, stride-1 in u (no conflicts)
    #pragma unroll
    for (int k = 0; k < 4; ++k) {
        const int idx = tid + k * 256;
        const int r = idx >> 7, u = idx & (UNITS - 1);
        const float s = PROJ_SCALE *
            ((part[0][r][u] + part[1][r][u]) + (part[2][r][u] + part[3][r][u]));
        const int row = row0 + r;
        if (isQ) {
            qbuf[(size_t)row * UNITS + u] = s;
        } else {
            const int bb = row >> 10, e = row & (ENC - 1);
            const int c = u >> 2, j = u & 3;
            kbufT[((size_t)bb * 32 * ENC + (size_t)c * ENC + e) * 4 + j] = s;
        }
    }
}

// rcp(1 + 2^a)  (a already includes the 2*log2e factor)
__device__ __forceinline__ float sig_r(float a) {
    return __builtin_amdgcn_rcpf(1.f + __builtin_amdgcn_exp2f(a));
}

// ---------------------------------------------------------------------------
// Kernel 2: scores + masked softmax. DQ=2 dec rows per block, 512 blocks x
// 1024 threads (16 waves): exactly 2 blocks/CU -> 32 waves/CU = 100%
// occupancy (round-4 was grid-capped at 30%). Each thread owns 1 e; kv loads
// shared across both dq rows. score = S0 - 2*sum_u scale_u*rcp(1+2^(q2+k2)).
// q/scale reads uniform (scalar pipe), k reads coalesced b128 from kbufT.
// XCD-swizzled: b pinned to an XCD pair so kbufT[b] (512 KB) stays in L2.
// ---------------------------------------------------------------------------
__global__ __launch_bounds__(1024) void score_kernel(
    const float* __restrict__ qbuf, const float* __restrict__ kbufT,
    const int* __restrict__ mask,   const float* __restrict__ scale,
    float* __restrict__ attn_out)
{
    const int bi  = blockIdx.x;                      // 0..511
    const int b   = (bi >> 1) & 3;                   // XCD-pair pinning
    const int dq0 = (((bi >> 3) << 1) | (bi & 1)) * 2;
    const int tid = threadIdx.x;                     // 0..1023 == e

    // S0 = sum(scale) — uniform scalar loop
    float S0 = 0.f;
    for (int j = 0; j < UNITS; j += 4) {
        const float4 sv = *(const float4*)(scale + j);
        S0 += (sv.x + sv.y) + (sv.z + sv.w);
    }

    const float* q0 = qbuf + (size_t)(b * DEC + dq0) * UNITS;
    const float* q1 = q0 + UNITS;
    const float* kc = kbufT + (size_t)b * 32 * ENC * 4 + (size_t)tid * 4;

    float t0 = 0.f, t1 = 0.f;
    for (int i = 0; i < 32; ++i) {
        const float4 qa = *(const float4*)(q0 + i * 4);       // uniform
        const float4 qb = *(const float4*)(q1 + i * 4);       // uniform
        const float4 sv = *(const float4*)(scale + i * 4);    // uniform
        const float4 kv = *(const float4*)(kc + (size_t)i * ENC * 4);  // coalesced b128
        t0 += sv.x * sig_r(qa.x + kv.x);
        t0 += sv.y * sig_r(qa.y + kv.y);
        t0 += sv.z * sig_r(qa.z + kv.z);
        t0 += sv.w * sig_r(qa.w + kv.w);
        t1 += sv.x * sig_r(qb.x + kv.x);
        t1 += sv.y * sig_r(qb.y + kv.y);
        t1 += sv.z * sig_r(qb.z + kv.z);
        t1 += sv.w * sig_r(qb.w + kv.w);
    }

    const int m = mask[b * ENC + tid];
    const float s0 = m ? (S0 - 2.f * t0) : -1e9f;
    const float s1 = m ? (S0 - 2.f * t1) : -1e9f;

    __shared__ float redm[2][16];
    __shared__ float reds[2][16];
    const int lane = tid & 63, wv = tid >> 6;   // 16 waves

    // max reduce (both dq rows together)
    float lm0 = s0, lm1 = s1;
    #pragma unroll
    for (int off = 32; off > 0; off >>= 1) {
        lm0 = fmaxf(lm0, __shfl_down(lm0, off, 64));
        lm1 = fmaxf(lm1, __shfl_down(lm1, off, 64));
    }
    if (lane == 0) { redm[0][wv] = lm0; redm[1][wv] = lm1; }
    __syncthreads();
    float gm0 = redm[0][0], gm1 = redm[1][0];
    #pragma unroll
    for (int w = 1; w < 16; ++w) {
        gm0 = fmaxf(gm0, redm[0][w]);
        gm1 = fmaxf(gm1, redm[1][w]);
    }

    // exp & sum
    const float w0 = __expf(s0 - gm0);
    const float w1 = __expf(s1 - gm1);
    float ls0 = w0, ls1 = w1;
    #pragma unroll
    for (int off = 32; off > 0; off >>= 1) {
        ls0 += __shfl_down(ls0, off, 64);
        ls1 += __shfl_down(ls1, off, 64);
    }
    if (lane == 0) { reds[0][wv] = ls0; reds[1][wv] = ls1; }
    __syncthreads();
    float gs0 = 0.f, gs1 = 0.f;
    #pragma unroll
    for (int w = 0; w < 16; ++w) { gs0 += reds[0][w]; gs1 += reds[1][w]; }
    const float inv0 = __builtin_amdgcn_rcpf(gs0);
    const float inv1 = __builtin_amdgcn_rcpf(gs1);

    float* a0 = attn_out + (size_t)(b * DEC + dq0) * ENC;
    attn_out[(size_t)(b * DEC + dq0) * ENC + tid]       = w0 * inv0;
    attn_out[(size_t)(b * DEC + dq0 + 1) * ENC + tid]   = w1 * inv1;
    (void)a0;
}

// ---------------------------------------------------------------------------
// Kernel 3: ctx = attn @ value. 512 blocks x 512 threads: 8 dec rows x 128
// h-cols per block. Attention rows staged in LDS; weights fetched as
// same-address ds_read_b128 broadcasts (free, and on the LDS pipe so they
// co-issue with the VALU fma stream — round-4 used v_readlane which burned
// 8 VALU ops per value-load). Each of 8 waves owns a 128-e slice; 8-way
// cross-wave reduce via LDS. 64 KB LDS -> 2 blocks/CU.
// ---------------------------------------------------------------------------
__global__ __launch_bounds__(512) void ctx_kernel(
    const float* __restrict__ attn, const float* __restrict__ value,
    float* __restrict__ ctx)
{
    __shared__ float attnS[8][ENC];     // 32 KB
    __shared__ float part[8][8][128];   // 32 KB

    const int bi   = blockIdx.x;                 // 0..511, XCD-swizzled
    const int b    = (bi >> 1) & 3;              // b pinned to an XCD pair
    const int idx  = ((bi >> 3) << 1) | (bi & 1);
    const int row0 = (idx >> 2) * 8;
    const int h0   = (idx & 3) * 128;
    const int tid  = threadIdx.x;
    const int lane = tid & 63;
    const int wv   = __builtin_amdgcn_readfirstlane(tid >> 6);  // 0..7

    // stage 8 attention rows (coalesced b64: 1024 e / 512 threads = 2 each)
    const float* ab = attn + (size_t)(b * DEC + row0) * ENC;
    #pragma unroll
    for (int r = 0; r < 8; ++r) {
        const float2 v = *(const float2*)(ab + (size_t)r * ENC + tid * 2);
        *(float2*)&attnS[r][tid * 2] = v;
    }
    __syncthreads();

    float acc[8][2];
    #pragma unroll
    for (int r = 0; r < 8; ++r) { acc[r][0] = 0.f; acc[r][1] = 0.f; }

    const float* vb = value + (size_t)b * ENC * HID + h0 + lane * 2;
    const int e0 = wv * 128;

    for (int g = 0; g < 32; ++g) {                // 4-e groups
        const int eg = e0 + g * 4;
        float4 w4[8];
        #pragma unroll
        for (int r = 0; r < 8; ++r)
            w4[r] = *(const float4*)&attnS[r][eg];   // same-addr broadcast b128
        const float* vp = vb + (size_t)eg * HID;
        #pragma unroll
        for (int j = 0; j < 4; ++j) {
            const float2 v2 = *(const float2*)(vp + (size_t)j * HID);  // coalesced b64
            const float* wj = (const float*)&w4[0] + j;
            #pragma unroll
            for (int r = 0; r < 8; ++r) {
                const float w = ((const float*)&w4[r])[j];
                acc[r][0] += w * v2.x;
                acc[r][1] += w * v2.y;
            }
            (void)wj;
        }
    }

    #pragma unroll
    for (int r = 0; r < 8; ++r)
        *(float2*)&part[wv][r][lane * 2] = make_float2(acc[r][0], acc[r][1]);
    __syncthreads();

    // 8-way cross-wave reduce: 1024 outputs, 2 per thread, stride-1 in h
    #pragma unroll
    for (int k = 0; k < 2; ++k) {
        const int idx2 = tid + k * 512;
        const int r = idx2 >> 7, hh = idx2 & 127;
        float s = 0.f;
        #pragma unroll
        for (int w = 0; w < 8; ++w) s += part[w][r][hh];
        ctx[(size_t)(b * DEC + row0 + r) * HID + h0 + hh] = s;
    }
}

extern "C" void kernel_launch(void* const* d_in, const int* in_sizes, int n_in,
                              void* d_out, int out_size, void* d_ws, size_t ws_size,
                              hipStream_t stream) {
    const float* query = (const float*)d_in[0];
    const float* value = (const float*)d_in[1];
    const int*   mask  = (const int*)  d_in[2];
    const float* W1    = (const float*)d_in[3];
    const float* W2    = (const float*)d_in[4];
    const float* scale = (const float*)d_in[5];

    float* qbuf  = (float*)d_ws;                       // B*DEC*UNITS   = 131072 floats
    float* kbufT = qbuf + (size_t)B * DEC * UNITS;     // B*32*ENC*4    = 524288 floats

    float* ctx_out  = (float*)d_out;                   // B*DEC*HID
    float* attn_out = ctx_out + (size_t)B * DEC * HID; // B*DEC*ENC

    proj_kernel <<<640,  256, 0, stream>>>(query, value, W1, W2, qbuf, kbufT);
    score_kernel<<<512, 1024, 0, stream>>>(qbuf, kbufT, mask, scale, attn_out);
    ctx_kernel  <<<512,  512, 0, stream>>>(attn_out, value, ctx_out);
}

// Round 6
// 148.281 us; speedup vs baseline: 1.5254x; 1.0084x over previous
//
#include <hip/hip_runtime.h>
#include <cstddef>

#define B     4
#define DEC   256
#define ENC   1024
#define HID   512
#define UNITS 128

// proj outputs are scaled by 2*log2(e) so the score kernel can use raw v_exp_f32
// (2^x) for tanh(x) = 1 - 2/(1+e^{2x}) = 1 - 2/(1+2^{(2*log2e)*x}).
#define PROJ_SCALE 2.8853900817779268f   // 2 * log2(e)

// ---------------------------------------------------------------------------
// Kernel 1: projections. Block = 8 rows x 128 units; each wave handles a
// 128-wide h-quarter (all 8 rows), partials reduced across waves via LDS.
// X reads are wave-uniform (scalar pipe); W reads lane-coalesced b32 from L2,
// software-pipelined depth-1 so the next h-group's 8 W loads are in flight
// during the current 64-fma burst (R5: VGPR=20-style serialization).
// q rows -> qbuf row-major; k rows -> kbufT [b][c=u/4][e][u%4].
// ---------------------------------------------------------------------------
__global__ __launch_bounds__(256) void proj_kernel(
    const float* __restrict__ query, const float* __restrict__ value,
    const float* __restrict__ W1,    const float* __restrict__ W2,
    float* __restrict__ qbuf,        float* __restrict__ kbufT)
{
    __shared__ float part[4][8][UNITS];   // 16 KB

    const int tid  = threadIdx.x;
    const int lane = tid & 63;
    const int wv   = __builtin_amdgcn_readfirstlane(tid >> 6);
    const int row0g = blockIdx.x * 8;
    const bool isQ = row0g < B * DEC;
    const float* X = isQ ? query : value;
    const float* W = isQ ? W1 : W2;
    const int row0 = isQ ? row0g : row0g - B * DEC;
    const int h0   = wv * 128;            // this wave's h-quarter

    float acc0[8], acc1[8];
    #pragma unroll
    for (int r = 0; r < 8; ++r) { acc0[r] = 0.f; acc1[r] = 0.f; }

    const float* Xb = X + (size_t)row0 * HID + h0;
    const float* Wb = W + (size_t)h0 * UNITS;

    // preload W group 0
    float wa[4], wb[4];
    #pragma unroll
    for (int j = 0; j < 4; ++j) {
        wa[j] = Wb[j * UNITS + lane];
        wb[j] = Wb[j * UNITS + 64 + lane];
    }

    for (int h = 0; h < 128; h += 4) {
        // prefetch next W group (clamped; last iteration reloads current)
        const int hp = (h + 4 < 128) ? h + 4 : h;
        float na[4], nb[4];
        #pragma unroll
        for (int j = 0; j < 4; ++j) {
            na[j] = Wb[(hp + j) * UNITS + lane];
            nb[j] = Wb[(hp + j) * UNITS + 64 + lane];
        }
        #pragma unroll
        for (int r = 0; r < 8; ++r) {
            const float4 xv = *(const float4*)(Xb + r * HID + h);  // wave-uniform
            acc0[r] += xv.x*wa[0] + xv.y*wa[1] + xv.z*wa[2] + xv.w*wa[3];
            acc1[r] += xv.x*wb[0] + xv.y*wb[1] + xv.z*wb[2] + xv.w*wb[3];
        }
        #pragma unroll
        for (int j = 0; j < 4; ++j) { wa[j] = na[j]; wb[j] = nb[j]; }
    }

    #pragma unroll
    for (int r = 0; r < 8; ++r) {
        part[wv][r][lane]      = acc0[r];
        part[wv][r][64 + lane] = acc1[r];
    }
    __syncthreads();

    // cross-wave reduce: 1024 outputs, 4 per thread, stride-1 in u (no conflicts)
    #pragma unroll
    for (int k = 0; k < 4; ++k) {
        const int idx = tid + k * 256;
        const int r = idx >> 7, u = idx & (UNITS - 1);
        const float s = PROJ_SCALE *
            ((part[0][r][u] + part[1][r][u]) + (part[2][r][u] + part[3][r][u]));
        const int row = row0 + r;
        if (isQ) {
            qbuf[(size_t)row * UNITS + u] = s;
        } else {
            const int bb = row >> 10, e = row & (ENC - 1);
            const int c = u >> 2, j = u & 3;
            kbufT[((size_t)bb * 32 * ENC + (size_t)c * ENC + e) * 4 + j] = s;
        }
    }
}

// rcp(1 + 2^a)  (a already includes the 2*log2e factor)
__device__ __forceinline__ float sig_r(float a) {
    return __builtin_amdgcn_rcpf(1.f + __builtin_amdgcn_exp2f(a));
}

// ---------------------------------------------------------------------------
// Kernel 2: scores + masked softmax. DQ=2 dec rows per block, 512 blocks x
// 1024 threads, 1 e per thread. R5 post-mortem: VGPR=20 meant ONE kv load in
// flight -> load/compute serialized (VALUBusy 62%). This version quad-buffers
// kv in registers: 4 chunks in flight covering ~700 cyc of sig compute vs
// ~200 cyc L2 latency. score = S0 - 2*sum_u scale_u*rcp(1+2^(q2+k2)).
// q/scale reads uniform (scalar pipe), k reads coalesced b128 from kbufT.
// XCD-swizzled: b pinned to an XCD pair so kbufT[b] (512 KB) stays in L2.
// ---------------------------------------------------------------------------
__global__ __launch_bounds__(1024) void score_kernel(
    const float* __restrict__ qbuf, const float* __restrict__ kbufT,
    const int* __restrict__ mask,   const float* __restrict__ scale,
    float* __restrict__ attn_out)
{
    const int bi  = blockIdx.x;                      // 0..511
    const int b   = (bi >> 1) & 3;                   // XCD-pair pinning
    const int dq0 = (((bi >> 3) << 1) | (bi & 1)) * 2;
    const int tid = threadIdx.x;                     // 0..1023 == e

    // S0 = sum(scale) — uniform scalar loop
    float S0 = 0.f;
    for (int j = 0; j < UNITS; j += 4) {
        const float4 sv = *(const float4*)(scale + j);
        S0 += (sv.x + sv.y) + (sv.z + sv.w);
    }

    const float* q0 = qbuf + (size_t)(b * DEC + dq0) * UNITS;
    const float* q1 = q0 + UNITS;
    const float* kc = kbufT + (size_t)b * 32 * ENC * 4 + (size_t)tid * 4;

    float t0 = 0.f, t1 = 0.f;

    // quad-buffered kv pipeline
    float4 kv0 = *(const float4*)(kc + (size_t)0 * ENC * 4);
    float4 kv1 = *(const float4*)(kc + (size_t)1 * ENC * 4);
    float4 kv2 = *(const float4*)(kc + (size_t)2 * ENC * 4);
    float4 kv3 = *(const float4*)(kc + (size_t)3 * ENC * 4);

    for (int i = 0; i < 32; i += 4) {
        const int ip = (i + 4 < 32) ? (i + 4) : i;   // clamped (last: redundant)
        float4 n0 = *(const float4*)(kc + (size_t)(ip + 0) * ENC * 4);
        float4 n1 = *(const float4*)(kc + (size_t)(ip + 1) * ENC * 4);
        float4 n2 = *(const float4*)(kc + (size_t)(ip + 2) * ENC * 4);
        float4 n3 = *(const float4*)(kc + (size_t)(ip + 3) * ENC * 4);

        #pragma unroll
        for (int j = 0; j < 4; ++j) {
            const float4 kv = (j == 0) ? kv0 : (j == 1) ? kv1 : (j == 2) ? kv2 : kv3;
            const int ii = i + j;
            const float4 qa = *(const float4*)(q0 + ii * 4);      // uniform
            const float4 qb = *(const float4*)(q1 + ii * 4);      // uniform
            const float4 sv = *(const float4*)(scale + ii * 4);   // uniform
            t0 += sv.x * sig_r(qa.x + kv.x);
            t0 += sv.y * sig_r(qa.y + kv.y);
            t0 += sv.z * sig_r(qa.z + kv.z);
            t0 += sv.w * sig_r(qa.w + kv.w);
            t1 += sv.x * sig_r(qb.x + kv.x);
            t1 += sv.y * sig_r(qb.y + kv.y);
            t1 += sv.z * sig_r(qb.z + kv.z);
            t1 += sv.w * sig_r(qb.w + kv.w);
        }
        kv0 = n0; kv1 = n1; kv2 = n2; kv3 = n3;
    }

    const int m = mask[b * ENC + tid];
    const float s0 = m ? (S0 - 2.f * t0) : -1e9f;
    const float s1 = m ? (S0 - 2.f * t1) : -1e9f;

    __shared__ float redm[2][16];
    __shared__ float reds[2][16];
    const int lane = tid & 63, wv = tid >> 6;   // 16 waves

    // max reduce (both dq rows together)
    float lm0 = s0, lm1 = s1;
    #pragma unroll
    for (int off = 32; off > 0; off >>= 1) {
        lm0 = fmaxf(lm0, __shfl_down(lm0, off, 64));
        lm1 = fmaxf(lm1, __shfl_down(lm1, off, 64));
    }
    if (lane == 0) { redm[0][wv] = lm0; redm[1][wv] = lm1; }
    __syncthreads();
    float gm0 = redm[0][0], gm1 = redm[1][0];
    #pragma unroll
    for (int w = 1; w < 16; ++w) {
        gm0 = fmaxf(gm0, redm[0][w]);
        gm1 = fmaxf(gm1, redm[1][w]);
    }

    // exp & sum
    const float w0 = __expf(s0 - gm0);
    const float w1 = __expf(s1 - gm1);
    float ls0 = w0, ls1 = w1;
    #pragma unroll
    for (int off = 32; off > 0; off >>= 1) {
        ls0 += __shfl_down(ls0, off, 64);
        ls1 += __shfl_down(ls1, off, 64);
    }
    if (lane == 0) { reds[0][wv] = ls0; reds[1][wv] = ls1; }
    __syncthreads();
    float gs0 = 0.f, gs1 = 0.f;
    #pragma unroll
    for (int w = 0; w < 16; ++w) { gs0 += reds[0][w]; gs1 += reds[1][w]; }
    const float inv0 = __builtin_amdgcn_rcpf(gs0);
    const float inv1 = __builtin_amdgcn_rcpf(gs1);

    attn_out[(size_t)(b * DEC + dq0) * ENC + tid]     = w0 * inv0;
    attn_out[(size_t)(b * DEC + dq0 + 1) * ENC + tid] = w1 * inv1;
}

// ---------------------------------------------------------------------------
// Kernel 3: ctx = attn @ value. 512 blocks x 512 threads: 8 dec rows x 128
// h-cols per block. Attention rows staged in LDS; weights fetched as
// same-address ds_read_b128 broadcasts (LDS pipe, co-issues with fma stream).
// Value loads software-pipelined: the next 4-e group's four b64 loads are in
// flight during the current group's 64-fma burst. 8-way cross-wave reduce.
// ---------------------------------------------------------------------------
__global__ __launch_bounds__(512) void ctx_kernel(
    const float* __restrict__ attn, const float* __restrict__ value,
    float* __restrict__ ctx)
{
    __shared__ float attnS[8][ENC];     // 32 KB
    __shared__ float part[8][8][128];   // 32 KB

    const int bi   = blockIdx.x;                 // 0..511, XCD-swizzled
    const int b    = (bi >> 1) & 3;              // b pinned to an XCD pair
    const int idx  = ((bi >> 3) << 1) | (bi & 1);
    const int row0 = (idx >> 2) * 8;
    const int h0   = (idx & 3) * 128;
    const int tid  = threadIdx.x;
    const int lane = tid & 63;
    const int wv   = __builtin_amdgcn_readfirstlane(tid >> 6);  // 0..7

    // stage 8 attention rows (coalesced b64: 1024 e / 512 threads = 2 each)
    const float* ab = attn + (size_t)(b * DEC + row0) * ENC;
    #pragma unroll
    for (int r = 0; r < 8; ++r) {
        const float2 v = *(const float2*)(ab + (size_t)r * ENC + tid * 2);
        *(float2*)&attnS[r][tid * 2] = v;
    }
    __syncthreads();

    float acc[8][2];
    #pragma unroll
    for (int r = 0; r < 8; ++r) { acc[r][0] = 0.f; acc[r][1] = 0.f; }

    const float* vb = value + (size_t)b * ENC * HID + h0 + lane * 2;
    const int e0 = wv * 128;

    // preload group 0's value columns
    float2 va[4];
    #pragma unroll
    for (int j = 0; j < 4; ++j)
        va[j] = *(const float2*)(vb + (size_t)(e0 + j) * HID);

    for (int g = 0; g < 32; ++g) {                // 4-e groups
        const int gp = (g + 1 < 32) ? g + 1 : g;  // clamped prefetch
        float2 vn[4];
        #pragma unroll
        for (int j = 0; j < 4; ++j)
            vn[j] = *(const float2*)(vb + (size_t)(e0 + gp * 4 + j) * HID);

        const int eg = e0 + g * 4;
        float4 w4[8];
        #pragma unroll
        for (int r = 0; r < 8; ++r)
            w4[r] = *(const float4*)&attnS[r][eg];   // same-addr broadcast b128

        #pragma unroll
        for (int j = 0; j < 4; ++j) {
            const float2 v2 = va[j];
            #pragma unroll
            for (int r = 0; r < 8; ++r) {
                const float w = ((const float*)&w4[r])[j];
                acc[r][0] += w * v2.x;
                acc[r][1] += w * v2.y;
            }
        }
        #pragma unroll
        for (int j = 0; j < 4; ++j) va[j] = vn[j];
    }

    #pragma unroll
    for (int r = 0; r < 8; ++r)
        *(float2*)&part[wv][r][lane * 2] = make_float2(acc[r][0], acc[r][1]);
    __syncthreads();

    // 8-way cross-wave reduce: 1024 outputs, 2 per thread, stride-1 in h
    #pragma unroll
    for (int k = 0; k < 2; ++k) {
        const int idx2 = tid + k * 512;
        const int r = idx2 >> 7, hh = idx2 & 127;
        float s = 0.f;
        #pragma unroll
        for (int w = 0; w < 8; ++w) s += part[w][r][hh];
        ctx[(size_t)(b * DEC + row0 + r) * HID + h0 + hh] = s;
    }
}

extern "C" void kernel_launch(void* const* d_in, const int* in_sizes, int n_in,
                              void* d_out, int out_size, void* d_ws, size_t ws_size,
                              hipStream_t stream) {
    const float* query = (const float*)d_in[0];
    const float* value = (const float*)d_in[1];
    const int*   mask  = (const int*)  d_in[2];
    const float* W1    = (const float*)d_in[3];
    const float* W2    = (const float*)d_in[4];
    const float* scale = (const float*)d_in[5];

    float* qbuf  = (float*)d_ws;                       // B*DEC*UNITS   = 131072 floats
    float* kbufT = qbuf + (size_t)B * DEC * UNITS;     // B*32*ENC*4    = 524288 floats

    float* ctx_out  = (float*)d_out;                   // B*DEC*HID
    float* attn_out = ctx_out + (size_t)B * DEC * HID; // B*DEC*ENC

    proj_kernel <<<640,  256, 0, stream>>>(query, value, W1, W2, qbuf, kbufT);
    score_kernel<<<512, 1024, 0, stream>>>(qbuf, kbufT, mask, scale, attn_out);
    ctx_kernel  <<<512,  512, 0, stream>>>(attn_out, value, ctx_out);
}

// Round 7
// 134.800 us; speedup vs baseline: 1.6779x; 1.1000x over previous
//
#include <hip/hip_runtime.h>
#include <cstddef>

#define B     4
#define DEC   256
#define ENC   1024
#define HID   512
#define UNITS 128

// proj outputs are EXPONENTIATED: Z = 2^(2*log2e * proj) so the score kernel
// computes tanh via  tanh(q+k) = 1 - 2/(1 + Zq*Zk)  with a single rcp and NO
// exp in the 134M-eval inner loop (exp moved to the 655K-eval proj epilogue).
#define PROJ_SCALE 2.8853900817779268f   // 2 * log2(e)

// ---------------------------------------------------------------------------
// Kernel 1: projections. Block = 8 rows x 128 units; each wave handles a
// 128-wide h-quarter (all 8 rows), partials reduced across waves via LDS.
// X reads are wave-uniform (scalar pipe); W reads lane-coalesced b32 from L2,
// depth-1 software prefetch. Epilogue applies 2^x. q rows -> qbuf row-major;
// k rows -> kbufT [b][c=u/4][e][u%4] so score k-loads are coalesced b128.
// ---------------------------------------------------------------------------
__global__ __launch_bounds__(256) void proj_kernel(
    const float* __restrict__ query, const float* __restrict__ value,
    const float* __restrict__ W1,    const float* __restrict__ W2,
    float* __restrict__ qbuf,        float* __restrict__ kbufT)
{
    __shared__ float part[4][8][UNITS];   // 16 KB

    const int tid  = threadIdx.x;
    const int lane = tid & 63;
    const int wv   = __builtin_amdgcn_readfirstlane(tid >> 6);
    const int row0g = blockIdx.x * 8;
    const bool isQ = row0g < B * DEC;
    const float* X = isQ ? query : value;
    const float* W = isQ ? W1 : W2;
    const int row0 = isQ ? row0g : row0g - B * DEC;
    const int h0   = wv * 128;            // this wave's h-quarter

    float acc0[8], acc1[8];
    #pragma unroll
    for (int r = 0; r < 8; ++r) { acc0[r] = 0.f; acc1[r] = 0.f; }

    const float* Xb = X + (size_t)row0 * HID + h0;
    const float* Wb = W + (size_t)h0 * UNITS;

    // preload W group 0
    float wa[4], wb[4];
    #pragma unroll
    for (int j = 0; j < 4; ++j) {
        wa[j] = Wb[j * UNITS + lane];
        wb[j] = Wb[j * UNITS + 64 + lane];
    }

    for (int h = 0; h < 128; h += 4) {
        // prefetch next W group (clamped; last iteration reloads current)
        const int hp = (h + 4 < 128) ? h + 4 : h;
        float na[4], nb[4];
        #pragma unroll
        for (int j = 0; j < 4; ++j) {
            na[j] = Wb[(hp + j) * UNITS + lane];
            nb[j] = Wb[(hp + j) * UNITS + 64 + lane];
        }
        #pragma unroll
        for (int r = 0; r < 8; ++r) {
            const float4 xv = *(const float4*)(Xb + r * HID + h);  // wave-uniform
            acc0[r] += xv.x*wa[0] + xv.y*wa[1] + xv.z*wa[2] + xv.w*wa[3];
            acc1[r] += xv.x*wb[0] + xv.y*wb[1] + xv.z*wb[2] + xv.w*wb[3];
        }
        #pragma unroll
        for (int j = 0; j < 4; ++j) { wa[j] = na[j]; wb[j] = nb[j]; }
    }

    #pragma unroll
    for (int r = 0; r < 8; ++r) {
        part[wv][r][lane]      = acc0[r];
        part[wv][r][64 + lane] = acc1[r];
    }
    __syncthreads();

    // cross-wave reduce + 2^x epilogue: 1024 outputs, 4 per thread
    #pragma unroll
    for (int k = 0; k < 4; ++k) {
        const int idx = tid + k * 256;
        const int r = idx >> 7, u = idx & (UNITS - 1);
        const float s = PROJ_SCALE *
            ((part[0][r][u] + part[1][r][u]) + (part[2][r][u] + part[3][r][u]));
        const float z = __builtin_amdgcn_exp2f(s);   // Z = 2^(2*log2e*proj)
        const int row = row0 + r;
        if (isQ) {
            qbuf[(size_t)row * UNITS + u] = z;
        } else {
            const int bb = row >> 10, e = row & (ENC - 1);
            const int c = u >> 2, j = u & 3;
            kbufT[((size_t)bb * 32 * ENC + (size_t)c * ENC + e) * 4 + j] = z;
        }
    }
}

// ---------------------------------------------------------------------------
// Kernel 2: scores + masked softmax. DQ=4 dec rows per block, 256 blocks x
// 1024 threads, 1 e per thread. Inner step is 3 VALU / 1 trans per sigmoid:
//   t += scale_u * rcp(fma(Zq, Zk, 1))        (exp was hoisted into proj)
// vs round-6's 5 VALU / 2 trans — the score floor halves. 16 independent
// sigmoids per kv load hide L2 latency. q/scale reads uniform (scalar pipe),
// k reads coalesced b128. XCD-swizzled: b pinned to an XCD pair.
// ---------------------------------------------------------------------------
__global__ __launch_bounds__(1024) void score_kernel(
    const float* __restrict__ qbuf, const float* __restrict__ kbufT,
    const int* __restrict__ mask,   const float* __restrict__ scale,
    float* __restrict__ attn_out)
{
    const int bi  = blockIdx.x;                      // 0..255
    const int b   = (bi >> 1) & 3;                   // XCD-pair pinning
    const int dq0 = (((bi >> 3) << 1) | (bi & 1)) * 4;
    const int tid = threadIdx.x;                     // 0..1023 == e

    // S0 = sum(scale) — uniform scalar loop
    float S0 = 0.f;
    for (int j = 0; j < UNITS; j += 4) {
        const float4 sv = *(const float4*)(scale + j);
        S0 += (sv.x + sv.y) + (sv.z + sv.w);
    }

    const float* q0 = qbuf + (size_t)(b * DEC + dq0) * UNITS;
    const float* kc = kbufT + (size_t)b * 32 * ENC * 4 + (size_t)tid * 4;

    float t0 = 0.f, t1 = 0.f, t2 = 0.f, t3 = 0.f;

    float4 kv = *(const float4*)kc;                  // double-buffered kv
    for (int i = 0; i < 32; ++i) {
        float4 nkv;
        if (i + 1 < 32) nkv = *(const float4*)(kc + (size_t)(i + 1) * ENC * 4);
        const float4 sv = *(const float4*)(scale + i * 4);              // uniform
        const float4 qa = *(const float4*)(q0 + 0 * UNITS + i * 4);     // uniform
        const float4 qb = *(const float4*)(q0 + 1 * UNITS + i * 4);
        const float4 qc = *(const float4*)(q0 + 2 * UNITS + i * 4);
        const float4 qd = *(const float4*)(q0 + 3 * UNITS + i * 4);

        t0 += sv.x * __builtin_amdgcn_rcpf(fmaf(qa.x, kv.x, 1.f));
        t0 += sv.y * __builtin_amdgcn_rcpf(fmaf(qa.y, kv.y, 1.f));
        t0 += sv.z * __builtin_amdgcn_rcpf(fmaf(qa.z, kv.z, 1.f));
        t0 += sv.w * __builtin_amdgcn_rcpf(fmaf(qa.w, kv.w, 1.f));
        t1 += sv.x * __builtin_amdgcn_rcpf(fmaf(qb.x, kv.x, 1.f));
        t1 += sv.y * __builtin_amdgcn_rcpf(fmaf(qb.y, kv.y, 1.f));
        t1 += sv.z * __builtin_amdgcn_rcpf(fmaf(qb.z, kv.z, 1.f));
        t1 += sv.w * __builtin_amdgcn_rcpf(fmaf(qb.w, kv.w, 1.f));
        t2 += sv.x * __builtin_amdgcn_rcpf(fmaf(qc.x, kv.x, 1.f));
        t2 += sv.y * __builtin_amdgcn_rcpf(fmaf(qc.y, kv.y, 1.f));
        t2 += sv.z * __builtin_amdgcn_rcpf(fmaf(qc.z, kv.z, 1.f));
        t2 += sv.w * __builtin_amdgcn_rcpf(fmaf(qc.w, kv.w, 1.f));
        t3 += sv.x * __builtin_amdgcn_rcpf(fmaf(qd.x, kv.x, 1.f));
        t3 += sv.y * __builtin_amdgcn_rcpf(fmaf(qd.y, kv.y, 1.f));
        t3 += sv.z * __builtin_amdgcn_rcpf(fmaf(qd.z, kv.z, 1.f));
        t3 += sv.w * __builtin_amdgcn_rcpf(fmaf(qd.w, kv.w, 1.f));

        if (i + 1 < 32) kv = nkv;
    }

    const int m = mask[b * ENC + tid];
    float s[4];
    s[0] = m ? (S0 - 2.f * t0) : -1e9f;
    s[1] = m ? (S0 - 2.f * t1) : -1e9f;
    s[2] = m ? (S0 - 2.f * t2) : -1e9f;
    s[3] = m ? (S0 - 2.f * t3) : -1e9f;

    __shared__ float redm[4][16];
    __shared__ float reds[4][16];
    const int lane = tid & 63, wv = tid >> 6;   // 16 waves

    // max reduce (4 rows)
    float lm[4] = {s[0], s[1], s[2], s[3]};
    #pragma unroll
    for (int off = 32; off > 0; off >>= 1) {
        #pragma unroll
        for (int r = 0; r < 4; ++r)
            lm[r] = fmaxf(lm[r], __shfl_down(lm[r], off, 64));
    }
    if (lane == 0) {
        #pragma unroll
        for (int r = 0; r < 4; ++r) redm[r][wv] = lm[r];
    }
    __syncthreads();
    float gm[4];
    #pragma unroll
    for (int r = 0; r < 4; ++r) {
        float g = redm[r][0];
        #pragma unroll
        for (int w = 1; w < 16; ++w) g = fmaxf(g, redm[r][w]);
        gm[r] = g;
    }

    // exp & sum
    float wgt[4], ls[4];
    #pragma unroll
    for (int r = 0; r < 4; ++r) { wgt[r] = __expf(s[r] - gm[r]); ls[r] = wgt[r]; }
    #pragma unroll
    for (int off = 32; off > 0; off >>= 1) {
        #pragma unroll
        for (int r = 0; r < 4; ++r)
            ls[r] += __shfl_down(ls[r], off, 64);
    }
    if (lane == 0) {
        #pragma unroll
        for (int r = 0; r < 4; ++r) reds[r][wv] = ls[r];
    }
    __syncthreads();
    #pragma unroll
    for (int r = 0; r < 4; ++r) {
        float g = 0.f;
        #pragma unroll
        for (int w = 0; w < 16; ++w) g += reds[r][w];
        attn_out[(size_t)(b * DEC + dq0 + r) * ENC + tid] =
            wgt[r] * __builtin_amdgcn_rcpf(g);
    }
}

// ---------------------------------------------------------------------------
// Kernel 3: ctx = attn @ value. 512 blocks x 512 threads: 8 dec rows x 128
// h-cols per block. Attention rows staged in LDS; weights fetched as
// same-address ds_read_b128 broadcasts (LDS pipe, co-issues with fma stream).
// Value loads software-pipelined depth-1. 8-way cross-wave reduce via LDS.
// ---------------------------------------------------------------------------
__global__ __launch_bounds__(512) void ctx_kernel(
    const float* __restrict__ attn, const float* __restrict__ value,
    float* __restrict__ ctx)
{
    __shared__ float attnS[8][ENC];     // 32 KB
    __shared__ float part[8][8][128];   // 32 KB

    const int bi   = blockIdx.x;                 // 0..511, XCD-swizzled
    const int b    = (bi >> 1) & 3;              // b pinned to an XCD pair
    const int idx  = ((bi >> 3) << 1) | (bi & 1);
    const int row0 = (idx >> 2) * 8;
    const int h0   = (idx & 3) * 128;
    const int tid  = threadIdx.x;
    const int lane = tid & 63;
    const int wv   = __builtin_amdgcn_readfirstlane(tid >> 6);  // 0..7

    // stage 8 attention rows (coalesced b64: 1024 e / 512 threads = 2 each)
    const float* ab = attn + (size_t)(b * DEC + row0) * ENC;
    #pragma unroll
    for (int r = 0; r < 8; ++r) {
        const float2 v = *(const float2*)(ab + (size_t)r * ENC + tid * 2);
        *(float2*)&attnS[r][tid * 2] = v;
    }
    __syncthreads();

    float acc[8][2];
    #pragma unroll
    for (int r = 0; r < 8; ++r) { acc[r][0] = 0.f; acc[r][1] = 0.f; }

    const float* vb = value + (size_t)b * ENC * HID + h0 + lane * 2;
    const int e0 = wv * 128;

    // preload group 0's value columns
    float2 va[4];
    #pragma unroll
    for (int j = 0; j < 4; ++j)
        va[j] = *(const float2*)(vb + (size_t)(e0 + j) * HID);

    for (int g = 0; g < 32; ++g) {                // 4-e groups
        const int gp = (g + 1 < 32) ? g + 1 : g;  // clamped prefetch
        float2 vn[4];
        #pragma unroll
        for (int j = 0; j < 4; ++j)
            vn[j] = *(const float2*)(vb + (size_t)(e0 + gp * 4 + j) * HID);

        const int eg = e0 + g * 4;
        float4 w4[8];
        #pragma unroll
        for (int r = 0; r < 8; ++r)
            w4[r] = *(const float4*)&attnS[r][eg];   // same-addr broadcast b128

        #pragma unroll
        for (int j = 0; j < 4; ++j) {
            const float2 v2 = va[j];
            #pragma unroll
            for (int r = 0; r < 8; ++r) {
                const float w = ((const float*)&w4[r])[j];
                acc[r][0] += w * v2.x;
                acc[r][1] += w * v2.y;
            }
        }
        #pragma unroll
        for (int j = 0; j < 4; ++j) va[j] = vn[j];
    }

    #pragma unroll
    for (int r = 0; r < 8; ++r)
        *(float2*)&part[wv][r][lane * 2] = make_float2(acc[r][0], acc[r][1]);
    __syncthreads();

    // 8-way cross-wave reduce: 1024 outputs, 2 per thread, stride-1 in h
    #pragma unroll
    for (int k = 0; k < 2; ++k) {
        const int idx2 = tid + k * 512;
        const int r = idx2 >> 7, hh = idx2 & 127;
        float s = 0.f;
        #pragma unroll
        for (int w = 0; w < 8; ++w) s += part[w][r][hh];
        ctx[(size_t)(b * DEC + row0 + r) * HID + h0 + hh] = s;
    }
}

extern "C" void kernel_launch(void* const* d_in, const int* in_sizes, int n_in,
                              void* d_out, int out_size, void* d_ws, size_t ws_size,
                              hipStream_t stream) {
    const float* query = (const float*)d_in[0];
    const float* value = (const float*)d_in[1];
    const int*   mask  = (const int*)  d_in[2];
    const float* W1    = (const float*)d_in[3];
    const float* W2    = (const float*)d_in[4];
    const float* scale = (const float*)d_in[5];

    float* qbuf  = (float*)d_ws;                       // B*DEC*UNITS   = 131072 floats
    float* kbufT = qbuf + (size_t)B * DEC * UNITS;     // B*32*ENC*4    = 524288 floats

    float* ctx_out  = (float*)d_out;                   // B*DEC*HID
    float* attn_out = ctx_out + (size_t)B * DEC * HID; // B*DEC*ENC

    proj_kernel <<<640,  256, 0, stream>>>(query, value, W1, W2, qbuf, kbufT);
    score_kernel<<<256, 1024, 0, stream>>>(qbuf, kbufT, mask, scale, attn_out);
    ctx_kernel  <<<512,  512, 0, stream>>>(attn_out, value, ctx_out);
}

// Round 8
// 133.525 us; speedup vs baseline: 1.6939x; 1.0095x over previous
//
#include <hip/hip_runtime.h>
#include <cstddef>

#define B     4
#define DEC   256
#define ENC   1024
#define HID   512
#define UNITS 128

// proj outputs are EXPONENTIATED: Z = 2^(2*log2e * proj) so the score kernel
// computes tanh via  tanh(q+k) = 1 - 2/(1 + Zq*Zk)  with a single rcp and NO
// exp in the 134M-eval inner loop (exp moved to the 655K-eval proj epilogue).
#define PROJ_SCALE 2.8853900817779268f   // 2 * log2(e)

// ---------------------------------------------------------------------------
// Kernel 1: projections. Block = 8 rows x 128 units; each wave handles a
// 128-wide h-quarter (all 8 rows), partials reduced across waves via LDS.
// X reads are wave-uniform (scalar pipe); W reads lane-coalesced b32 from L2,
// depth-1 software prefetch. Epilogue applies 2^x. q rows -> qbuf row-major;
// k rows -> kbufT [b][c=u/4][e][u%4] so score k-loads are coalesced b128.
// ---------------------------------------------------------------------------
__global__ __launch_bounds__(256) void proj_kernel(
    const float* __restrict__ query, const float* __restrict__ value,
    const float* __restrict__ W1,    const float* __restrict__ W2,
    float* __restrict__ qbuf,        float* __restrict__ kbufT)
{
    __shared__ float part[4][8][UNITS];   // 16 KB

    const int tid  = threadIdx.x;
    const int lane = tid & 63;
    const int wv   = __builtin_amdgcn_readfirstlane(tid >> 6);
    const int row0g = blockIdx.x * 8;
    const bool isQ = row0g < B * DEC;
    const float* X = isQ ? query : value;
    const float* W = isQ ? W1 : W2;
    const int row0 = isQ ? row0g : row0g - B * DEC;
    const int h0   = wv * 128;            // this wave's h-quarter

    float acc0[8], acc1[8];
    #pragma unroll
    for (int r = 0; r < 8; ++r) { acc0[r] = 0.f; acc1[r] = 0.f; }

    const float* Xb = X + (size_t)row0 * HID + h0;
    const float* Wb = W + (size_t)h0 * UNITS;

    // preload W group 0
    float wa[4], wb[4];
    #pragma unroll
    for (int j = 0; j < 4; ++j) {
        wa[j] = Wb[j * UNITS + lane];
        wb[j] = Wb[j * UNITS + 64 + lane];
    }

    for (int h = 0; h < 128; h += 4) {
        // prefetch next W group (clamped; last iteration reloads current)
        const int hp = (h + 4 < 128) ? h + 4 : h;
        float na[4], nb[4];
        #pragma unroll
        for (int j = 0; j < 4; ++j) {
            na[j] = Wb[(hp + j) * UNITS + lane];
            nb[j] = Wb[(hp + j) * UNITS + 64 + lane];
        }
        #pragma unroll
        for (int r = 0; r < 8; ++r) {
            const float4 xv = *(const float4*)(Xb + r * HID + h);  // wave-uniform
            acc0[r] += xv.x*wa[0] + xv.y*wa[1] + xv.z*wa[2] + xv.w*wa[3];
            acc1[r] += xv.x*wb[0] + xv.y*wb[1] + xv.z*wb[2] + xv.w*wb[3];
        }
        #pragma unroll
        for (int j = 0; j < 4; ++j) { wa[j] = na[j]; wb[j] = nb[j]; }
    }

    #pragma unroll
    for (int r = 0; r < 8; ++r) {
        part[wv][r][lane]      = acc0[r];
        part[wv][r][64 + lane] = acc1[r];
    }
    __syncthreads();

    // cross-wave reduce + 2^x epilogue: 1024 outputs, 4 per thread
    #pragma unroll
    for (int k = 0; k < 4; ++k) {
        const int idx = tid + k * 256;
        const int r = idx >> 7, u = idx & (UNITS - 1);
        const float s = PROJ_SCALE *
            ((part[0][r][u] + part[1][r][u]) + (part[2][r][u] + part[3][r][u]));
        const float z = __builtin_amdgcn_exp2f(s);   // Z = 2^(2*log2e*proj)
        const int row = row0 + r;
        if (isQ) {
            qbuf[(size_t)row * UNITS + u] = z;
        } else {
            const int bb = row >> 10, e = row & (ENC - 1);
            const int c = u >> 2, j = u & 3;
            kbufT[((size_t)bb * 32 * ENC + (size_t)c * ENC + e) * 4 + j] = z;
        }
    }
}

// ---------------------------------------------------------------------------
// Kernel 2: scores + masked softmax. DQ=4 dec rows per block, 256 blocks x
// 1024 threads, 1 e per thread. Inner step is 3 VALU / 1 trans per sigmoid:
//   t += scale_u * rcp(fma(Zq, Zk, 1))        (exp hoisted into proj)
// Softmax WITHOUT max-subtraction: |score| <= sum|scale| ~ 11, so exp() is
// safely in [2e-5, 6e4]; masked lanes contribute exactly 0 (never exp(-1e9)).
// This deletes a full cross-block reduction + one __syncthreads from the
// tail. q/scale reads uniform (scalar pipe), k reads coalesced b128.
// XCD-swizzled: b pinned to an XCD pair so kbufT[b] (512 KB) stays in L2.
// ---------------------------------------------------------------------------
__global__ __launch_bounds__(1024) void score_kernel(
    const float* __restrict__ qbuf, const float* __restrict__ kbufT,
    const int* __restrict__ mask,   const float* __restrict__ scale,
    float* __restrict__ attn_out)
{
    const int bi  = blockIdx.x;                      // 0..255
    const int b   = (bi >> 1) & 3;                   // XCD-pair pinning
    const int dq0 = (((bi >> 3) << 1) | (bi & 1)) * 4;
    const int tid = threadIdx.x;                     // 0..1023 == e

    const int m = mask[b * ENC + tid];               // early, independent load

    // S0 = sum(scale) — uniform scalar loop
    float S0 = 0.f;
    for (int j = 0; j < UNITS; j += 4) {
        const float4 sv = *(const float4*)(scale + j);
        S0 += (sv.x + sv.y) + (sv.z + sv.w);
    }

    const float* q0 = qbuf + (size_t)(b * DEC + dq0) * UNITS;
    const float* kc = kbufT + (size_t)b * 32 * ENC * 4 + (size_t)tid * 4;

    float t0 = 0.f, t1 = 0.f, t2 = 0.f, t3 = 0.f;

    float4 kv = *(const float4*)kc;                  // double-buffered kv
    for (int i = 0; i < 32; ++i) {
        float4 nkv;
        if (i + 1 < 32) nkv = *(const float4*)(kc + (size_t)(i + 1) * ENC * 4);
        const float4 sv = *(const float4*)(scale + i * 4);              // uniform
        const float4 qa = *(const float4*)(q0 + 0 * UNITS + i * 4);     // uniform
        const float4 qb = *(const float4*)(q0 + 1 * UNITS + i * 4);
        const float4 qc = *(const float4*)(q0 + 2 * UNITS + i * 4);
        const float4 qd = *(const float4*)(q0 + 3 * UNITS + i * 4);

        t0 += sv.x * __builtin_amdgcn_rcpf(fmaf(qa.x, kv.x, 1.f));
        t0 += sv.y * __builtin_amdgcn_rcpf(fmaf(qa.y, kv.y, 1.f));
        t0 += sv.z * __builtin_amdgcn_rcpf(fmaf(qa.z, kv.z, 1.f));
        t0 += sv.w * __builtin_amdgcn_rcpf(fmaf(qa.w, kv.w, 1.f));
        t1 += sv.x * __builtin_amdgcn_rcpf(fmaf(qb.x, kv.x, 1.f));
        t1 += sv.y * __builtin_amdgcn_rcpf(fmaf(qb.y, kv.y, 1.f));
        t1 += sv.z * __builtin_amdgcn_rcpf(fmaf(qb.z, kv.z, 1.f));
        t1 += sv.w * __builtin_amdgcn_rcpf(fmaf(qb.w, kv.w, 1.f));
        t2 += sv.x * __builtin_amdgcn_rcpf(fmaf(qc.x, kv.x, 1.f));
        t2 += sv.y * __builtin_amdgcn_rcpf(fmaf(qc.y, kv.y, 1.f));
        t2 += sv.z * __builtin_amdgcn_rcpf(fmaf(qc.z, kv.z, 1.f));
        t2 += sv.w * __builtin_amdgcn_rcpf(fmaf(qc.w, kv.w, 1.f));
        t3 += sv.x * __builtin_amdgcn_rcpf(fmaf(qd.x, kv.x, 1.f));
        t3 += sv.y * __builtin_amdgcn_rcpf(fmaf(qd.y, kv.y, 1.f));
        t3 += sv.z * __builtin_amdgcn_rcpf(fmaf(qd.z, kv.z, 1.f));
        t3 += sv.w * __builtin_amdgcn_rcpf(fmaf(qd.w, kv.w, 1.f));

        if (i + 1 < 32) kv = nkv;
    }

    // unnormalized weights; masked lanes contribute exactly 0
    float wgt[4];
    wgt[0] = m ? __expf(S0 - 2.f * t0) : 0.f;
    wgt[1] = m ? __expf(S0 - 2.f * t1) : 0.f;
    wgt[2] = m ? __expf(S0 - 2.f * t2) : 0.f;
    wgt[3] = m ? __expf(S0 - 2.f * t3) : 0.f;

    __shared__ float reds[4][16];
    const int lane = tid & 63, wv = tid >> 6;   // 16 waves

    float ls[4] = {wgt[0], wgt[1], wgt[2], wgt[3]};
    #pragma unroll
    for (int off = 32; off > 0; off >>= 1) {
        #pragma unroll
        for (int r = 0; r < 4; ++r)
            ls[r] += __shfl_down(ls[r], off, 64);
    }
    if (lane == 0) {
        #pragma unroll
        for (int r = 0; r < 4; ++r) reds[r][wv] = ls[r];
    }
    __syncthreads();
    #pragma unroll
    for (int r = 0; r < 4; ++r) {
        float g = 0.f;
        #pragma unroll
        for (int w = 0; w < 16; ++w) g += reds[r][w];
        attn_out[(size_t)(b * DEC + dq0 + r) * ENC + tid] =
            wgt[r] * __builtin_amdgcn_rcpf(g);
    }
}

// ---------------------------------------------------------------------------
// Kernel 3: ctx = attn @ value. 512 blocks x 512 threads: 8 dec rows x 128
// h-cols per block. Attention rows staged in LDS; weights fetched as
// same-address ds_read_b128 broadcasts (LDS pipe, co-issues with fma stream).
// Value loads software-pipelined depth-1. 8-way cross-wave reduce via LDS.
// ---------------------------------------------------------------------------
__global__ __launch_bounds__(512) void ctx_kernel(
    const float* __restrict__ attn, const float* __restrict__ value,
    float* __restrict__ ctx)
{
    __shared__ float attnS[8][ENC];     // 32 KB
    __shared__ float part[8][8][128];   // 32 KB

    const int bi   = blockIdx.x;                 // 0..511, XCD-swizzled
    const int b    = (bi >> 1) & 3;              // b pinned to an XCD pair
    const int idx  = ((bi >> 3) << 1) | (bi & 1);
    const int row0 = (idx >> 2) * 8;
    const int h0   = (idx & 3) * 128;
    const int tid  = threadIdx.x;
    const int lane = tid & 63;
    const int wv   = __builtin_amdgcn_readfirstlane(tid >> 6);  // 0..7

    // stage 8 attention rows (coalesced b64: 1024 e / 512 threads = 2 each)
    const float* ab = attn + (size_t)(b * DEC + row0) * ENC;
    #pragma unroll
    for (int r = 0; r < 8; ++r) {
        const float2 v = *(const float2*)(ab + (size_t)r * ENC + tid * 2);
        *(float2*)&attnS[r][tid * 2] = v;
    }
    __syncthreads();

    float acc[8][2];
    #pragma unroll
    for (int r = 0; r < 8; ++r) { acc[r][0] = 0.f; acc[r][1] = 0.f; }

    const float* vb = value + (size_t)b * ENC * HID + h0 + lane * 2;
    const int e0 = wv * 128;

    // preload group 0's value columns
    float2 va[4];
    #pragma unroll
    for (int j = 0; j < 4; ++j)
        va[j] = *(const float2*)(vb + (size_t)(e0 + j) * HID);

    for (int g = 0; g < 32; ++g) {                // 4-e groups
        const int gp = (g + 1 < 32) ? g + 1 : g;  // clamped prefetch
        float2 vn[4];
        #pragma unroll
        for (int j = 0; j < 4; ++j)
            vn[j] = *(const float2*)(vb + (size_t)(e0 + gp * 4 + j) * HID);

        const int eg = e0 + g * 4;
        float4 w4[8];
        #pragma unroll
        for (int r = 0; r < 8; ++r)
            w4[r] = *(const float4*)&attnS[r][eg];   // same-addr broadcast b128

        #pragma unroll
        for (int j = 0; j < 4; ++j) {
            const float2 v2 = va[j];
            #pragma unroll
            for (int r = 0; r < 8; ++r) {
                const float w = ((const float*)&w4[r])[j];
                acc[r][0] += w * v2.x;
                acc[r][1] += w * v2.y;
            }
        }
        #pragma unroll
        for (int j = 0; j < 4; ++j) va[j] = vn[j];
    }

    #pragma unroll
    for (int r = 0; r < 8; ++r)
        *(float2*)&part[wv][r][lane * 2] = make_float2(acc[r][0], acc[r][1]);
    __syncthreads();

    // 8-way cross-wave reduce: 1024 outputs, 2 per thread, stride-1 in h
    #pragma unroll
    for (int k = 0; k < 2; ++k) {
        const int idx2 = tid + k * 512;
        const int r = idx2 >> 7, hh = idx2 & 127;
        float s = 0.f;
        #pragma unroll
        for (int w = 0; w < 8; ++w) s += part[w][r][hh];
        ctx[(size_t)(b * DEC + row0 + r) * HID + h0 + hh] = s;
    }
}

extern "C" void kernel_launch(void* const* d_in, const int* in_sizes, int n_in,
                              void* d_out, int out_size, void* d_ws, size_t ws_size,
                              hipStream_t stream) {
    const float* query = (const float*)d_in[0];
    const float* value = (const float*)d_in[1];
    const int*   mask  = (const int*)  d_in[2];
    const float* W1    = (const float*)d_in[3];
    const float* W2    = (const float*)d_in[4];
    const float* scale = (const float*)d_in[5];

    float* qbuf  = (float*)d_ws;                       // B*DEC*UNITS   = 131072 floats
    float* kbufT = qbuf + (size_t)B * DEC * UNITS;     // B*32*ENC*4    = 524288 floats

    float* ctx_out  = (float*)d_out;                   // B*DEC*HID
    float* attn_out = ctx_out + (size_t)B * DEC * HID; // B*DEC*ENC

    proj_kernel <<<640,  256, 0, stream>>>(query, value, W1, W2, qbuf, kbufT);
    score_kernel<<<256, 1024, 0, stream>>>(qbuf, kbufT, mask, scale, attn_out);
    ctx_kernel  <<<512,  512, 0, stream>>>(attn_out, value, ctx_out);
}